// Round 11
// baseline (29.807 us; speedup 1.0000x reference)
//
#include <hip/hip_runtime.h>

// Bottom-up HTMM forward. One block per (tree, generator); 16 groups of 16
// lanes. Group grp evaluates sibling subtrees {2grp,2grp+1} as one float2
// register chain, finishing with their level-4 parent in-chain. 16x16 matvec
// via hand-fused v_fmac_f32_dpp (row_ror); reductions via v_add_f32_dpp.
// Nodes return RAW beliefs; the parent reduces both children with ONE
// grpsum4 (batched), logs log2(nuL*nuR), and rcp-combines.
// launch_bounds(256,5): cap VGPR <=96 -> 5 waves/SIMD (pool 512, m69).
#define G_   8
#define NT_  128
#define NPT_ 1023

typedef float f16v __attribute__((ext_vector_type(16)));
#define RCP(x) __builtin_amdgcn_rcpf(x)

// lane i receives v[(i - R) & 15] within its 16-lane row (row_ror)
template<int R>
__device__ __forceinline__ float rotr16(float v) {
  return __int_as_float(__builtin_amdgcn_update_dpp(
      0, __float_as_int(v), 0x120 | R, 0xF, 0xF, true));
}
// builtin-path reduces (compiler handles DPP hazards) — prologue/top only
__device__ __forceinline__ float grpsum16(float v) {
  v += rotr16<8>(v); v += rotr16<4>(v); v += rotr16<2>(v); v += rotr16<1>(v);
  return v;
}
__device__ __forceinline__ float grpmax16(float v) {
  v = fmaxf(v, rotr16<8>(v)); v = fmaxf(v, rotr16<4>(v));
  v = fmaxf(v, rotr16<2>(v)); v = fmaxf(v, rotr16<1>(v));
  return v;
}

// ---- hot path: 4 dots with fused v_fmac_f32_dpp. Round-robin over 4
// accumulators: self-dep distance 4 >= FMA latency; s_nop 1 guards entry.
#define FMAC4_R(R) \
  asm("v_fmac_f32_dpp %0, %4, %8 row_ror:" #R " row_mask:0xf bank_mask:0xf\n\t" \
      "v_fmac_f32_dpp %1, %5, %8 row_ror:" #R " row_mask:0xf bank_mask:0xf\n\t" \
      "v_fmac_f32_dpp %2, %6, %9 row_ror:" #R " row_mask:0xf bank_mask:0xf\n\t" \
      "v_fmac_f32_dpp %3, %7, %9 row_ror:" #R " row_mask:0xf bank_mask:0xf"     \
      : "+v"(aLx), "+v"(aLy), "+v"(aRx), "+v"(aRy)                              \
      : "v"(vLx), "v"(vLy), "v"(vRx), "v"(vRy), "v"(w0[R]), "v"(w1[R]))
#define FMAC4_FIRST(R) \
  asm("s_nop 1\n\t"                                                             \
      "v_fmac_f32_dpp %0, %4, %8 row_ror:" #R " row_mask:0xf bank_mask:0xf\n\t" \
      "v_fmac_f32_dpp %1, %5, %8 row_ror:" #R " row_mask:0xf bank_mask:0xf\n\t" \
      "v_fmac_f32_dpp %2, %6, %9 row_ror:" #R " row_mask:0xf bank_mask:0xf\n\t" \
      "v_fmac_f32_dpp %3, %7, %9 row_ror:" #R " row_mask:0xf bank_mask:0xf"     \
      : "+v"(aLx), "+v"(aLy), "+v"(aRx), "+v"(aRy)                              \
      : "v"(vLx), "v"(vLy), "v"(vRx), "v"(vRy), "v"(w0[R]), "v"(w1[R]))

__device__ __forceinline__ void dot4(float vLx, float vLy, float vRx, float vRy,
                                     const f16v& w0, const f16v& w1,
                                     float& oLx, float& oLy, float& oRx, float& oRy) {
  float aLx = vLx * w0[0];
  float aLy = vLy * w0[0];
  float aRx = vRx * w1[0];
  float aRy = vRy * w1[0];
  FMAC4_FIRST(1);
  FMAC4_R(2);  FMAC4_R(3);  FMAC4_R(4);  FMAC4_R(5);
  FMAC4_R(6);  FMAC4_R(7);  FMAC4_R(8);  FMAC4_R(9);
  FMAC4_R(10); FMAC4_R(11); FMAC4_R(12); FMAC4_R(13);
  FMAC4_R(14); FMAC4_R(15);
  oLx = aLx; oLy = aLy; oRx = aRx; oRy = aRy;
}

// ---- 2 dots fused (parent node + top phase)
#define FMAC2_R(R) \
  asm("v_fmac_f32_dpp %0, %2, %4 row_ror:" #R " row_mask:0xf bank_mask:0xf\n\t" \
      "v_fmac_f32_dpp %1, %3, %5 row_ror:" #R " row_mask:0xf bank_mask:0xf"     \
      : "+v"(aL), "+v"(aR)                                                      \
      : "v"(vL), "v"(vR), "v"(w0[R]), "v"(w1[R]))
#define FMAC2_FIRST(R) \
  asm("s_nop 1\n\t"                                                             \
      "v_fmac_f32_dpp %0, %2, %4 row_ror:" #R " row_mask:0xf bank_mask:0xf\n\t" \
      "v_fmac_f32_dpp %1, %3, %5 row_ror:" #R " row_mask:0xf bank_mask:0xf"     \
      : "+v"(aL), "+v"(aR)                                                      \
      : "v"(vL), "v"(vR), "v"(w0[R]), "v"(w1[R]))

__device__ __forceinline__ void dot2f(float vL, float vR,
                                      const f16v& w0, const f16v& w1,
                                      float& oL, float& oR) {
  float aL = vL * w0[0];
  float aR = vR * w1[0];
  FMAC2_FIRST(1);
  FMAC2_R(2);  FMAC2_R(3);  FMAC2_R(4);  FMAC2_R(5);
  FMAC2_R(6);  FMAC2_R(7);  FMAC2_R(8);  FMAC2_R(9);
  FMAC2_R(10); FMAC2_R(11); FMAC2_R(12); FMAC2_R(13);
  FMAC2_R(14); FMAC2_R(15);
  oL = aL; oR = aR;
}

// dual 16-lane sum via v_add_f32_dpp; s_nops cover the same-reg
// VALU-write -> DPP-read hazard the compiler can't see.
__device__ __forceinline__ void grpsum2(float rx, float ry, float& nux, float& nuy) {
  asm("s_nop 1\n\t"
      "v_add_f32_dpp %0, %2, %2 row_ror:8 row_mask:0xf bank_mask:0xf\n\t"
      "v_add_f32_dpp %1, %3, %3 row_ror:8 row_mask:0xf bank_mask:0xf\n\t"
      "s_nop 0\n\t"
      "v_add_f32_dpp %0, %0, %0 row_ror:4 row_mask:0xf bank_mask:0xf\n\t"
      "v_add_f32_dpp %1, %1, %1 row_ror:4 row_mask:0xf bank_mask:0xf\n\t"
      "s_nop 0\n\t"
      "v_add_f32_dpp %0, %0, %0 row_ror:2 row_mask:0xf bank_mask:0xf\n\t"
      "v_add_f32_dpp %1, %1, %1 row_ror:2 row_mask:0xf bank_mask:0xf\n\t"
      "s_nop 0\n\t"
      "v_add_f32_dpp %0, %0, %0 row_ror:1 row_mask:0xf bank_mask:0xf\n\t"
      "v_add_f32_dpp %1, %1, %1 row_ror:1 row_mask:0xf bank_mask:0xf"
      : "=&v"(nux), "=&v"(nuy)
      : "v"(rx), "v"(ry));
}

// quad 16-lane sum: 4 interleaved DPP chains, round-robin distance 4;
// s_nop 1 at entry guards freshly-written inputs.
__device__ __forceinline__ void grpsum4(float r0, float r1, float r2, float r3,
                                        float& n0, float& n1, float& n2, float& n3) {
  asm("s_nop 1\n\t"
      "v_add_f32_dpp %0, %4, %4 row_ror:8 row_mask:0xf bank_mask:0xf\n\t"
      "v_add_f32_dpp %1, %5, %5 row_ror:8 row_mask:0xf bank_mask:0xf\n\t"
      "v_add_f32_dpp %2, %6, %6 row_ror:8 row_mask:0xf bank_mask:0xf\n\t"
      "v_add_f32_dpp %3, %7, %7 row_ror:8 row_mask:0xf bank_mask:0xf\n\t"
      "v_add_f32_dpp %0, %0, %0 row_ror:4 row_mask:0xf bank_mask:0xf\n\t"
      "v_add_f32_dpp %1, %1, %1 row_ror:4 row_mask:0xf bank_mask:0xf\n\t"
      "v_add_f32_dpp %2, %2, %2 row_ror:4 row_mask:0xf bank_mask:0xf\n\t"
      "v_add_f32_dpp %3, %3, %3 row_ror:4 row_mask:0xf bank_mask:0xf\n\t"
      "v_add_f32_dpp %0, %0, %0 row_ror:2 row_mask:0xf bank_mask:0xf\n\t"
      "v_add_f32_dpp %1, %1, %1 row_ror:2 row_mask:0xf bank_mask:0xf\n\t"
      "v_add_f32_dpp %2, %2, %2 row_ror:2 row_mask:0xf bank_mask:0xf\n\t"
      "v_add_f32_dpp %3, %3, %3 row_ror:2 row_mask:0xf bank_mask:0xf\n\t"
      "v_add_f32_dpp %0, %0, %0 row_ror:1 row_mask:0xf bank_mask:0xf\n\t"
      "v_add_f32_dpp %1, %1, %1 row_ror:1 row_mask:0xf bank_mask:0xf\n\t"
      "v_add_f32_dpp %2, %2, %2 row_ror:1 row_mask:0xf bank_mask:0xf\n\t"
      "v_add_f32_dpp %3, %3, %3 row_ror:1 row_mask:0xf bank_mask:0xf"
      : "=&v"(n0), "=&v"(n1), "=&v"(n2), "=&v"(n3)
      : "v"(r0), "v"(r1), "v"(r2), "v"(r3));
}

// Post-order evaluation of two sibling depth-5 subtrees (float2 .x/.y).
// Returns this node's RAW belief (unnormalized). Children's nus are reduced
// HERE (one grpsum4 for both), logged pairwise, and rcp-folded into the
// combine — identical math to per-node normalization, fewer reduce passes.
template<int DELTA, int J>
__device__ __forceinline__ void evalN(const float* __restrict__ sBa,
                                      const f16v& w0, const f16v& w1,
                                      const f16v& lfx, const f16v& lfy,
                                      int intp, float2& ll, float2& raw) {
  // prefetch this node's B-gather before descending (hides LDS latency)
  int xp = __shfl(intp, (1 << DELTA) - 1 + J, 16);
  float bvA = sBa[xp & 0xFFFF];
  float bvB = sBa[((unsigned)xp) >> 16];
  float2 rawL, rawR;
  if constexpr (DELTA == 3) {
    rawL.x = lfx[2 * J];     rawL.y = lfy[2 * J];
    rawR.x = lfx[2 * J + 1]; rawR.y = lfy[2 * J + 1];
  } else {
    evalN<DELTA + 1, 2 * J>(sBa, w0, w1, lfx, lfy, intp, ll, rawL);
    evalN<DELTA + 1, 2 * J + 1>(sBa, w0, w1, lfx, lfy, intp, ll, rawR);
  }
  float nLx, nLy, nRx, nRy;
  grpsum4(rawL.x, rawL.y, rawR.x, rawR.y, nLx, nLy, nRx, nRy);
  ll.x += __log2f(nLx * nRx);
  ll.y += __log2f(nLy * nRy);
  float rLx = RCP(nLx), rLy = RCP(nLy);
  float rRx = RCP(nRx), rRy = RCP(nRy);
  float dLx, dLy, dRx, dRy;
  dot4(rawL.x, rawL.y, rawR.x, rawR.y, w0, w1, dLx, dLy, dRx, dRy);
  raw.x = fmaf(dLx, rLx, dRx * rRx) * bvA;
  raw.y = fmaf(dLy, rLy, dRy * rRy) * bvB;
}

template<bool SYNC>
__device__ __forceinline__ void topStep(const float* __restrict__ child,
                                        float* parent, int U, int lvl,
                                        const float* __restrict__ sB,
                                        const f16v& w0, const f16v& w1,
                                        int a, int grp, int topx, float& ll) {
  int j = (grp < U) ? grp : 0;            // clamp: keep full-wave EXEC for DPP
  int node = (1 << lvl) - 1 + j;
  int xi = __shfl(topx, node, 64);
  float bval = sB[xi * 17 + a];
  float vL = child[(2 * j) * 17 + a];
  float vR = child[(2 * j + 1) * 17 + a];
  float dL, dR;
  dot2f(vL, vR, w0, w1, dL, dR);
  float bu = (dL + dR) * bval;
  float nu = grpsum16(bu);
  if (grp < U) {
    ll += __log2f(nu);
    if (parent) parent[grp * 17 + a] = bu * RCP(nu);
  }
  if constexpr (SYNC) __syncthreads();
}

__global__ __launch_bounds__(256, 5) void htmm_fwd_kernel(
    const float* __restrict__ lA,   // (16,16,2,8)
    const float* __restrict__ lB,   // (16,256,8)
    const float* __restrict__ lPi,  // (16,2,8)
    const float* __restrict__ lSP,  // (2,8)
    const int*   __restrict__ x,    // (128*1023,)
    float*       __restrict__ out)  // (128,8)
{
  __shared__ float sB[256 * 17];    // normalized B, [m][c], stride 17
  __shared__ float sA[2 * 16 * 16]; // normalized A, [l][b][a]
  __shared__ float sPi[32];         // [l][c]
  __shared__ float roots[16 * 17];  // level-4 beliefs (normalized)
  __shared__ float topA[8 * 17];
  __shared__ float topB[4 * 17];
  __shared__ float red[4];

  const int tid = threadIdx.x;
  const int bid = blockIdx.x;       // tree*8 + g
  const int T   = bid >> 3;
  const int g   = bid & 7;
  const int a   = tid & 15;
  const int grp = tid >> 4;
  const long base = (long)T * NPT_;
  const int sx = 2 * grp;           // left sibling subtree
  const int sy = 2 * grp + 1;       // right sibling subtree

  // ---- ALL global x loads first: latency hides under the softmax prologue --
  int lxA = x[base + 511 + 16 * sx + a] * 17;
  int lxB = x[base + 511 + 16 * sy + a] * 17;
  int leafp = lxA | (lxB << 16);
  int dpl = 31 - __clz(a + 1);
  int iA = (a < 15) ? x[base + ((31 + sx) << dpl) + a] * 17 : 0;
  int iB = (a < 15) ? x[base + ((31 + sy) << dpl) + a] * 17 : 0;
  int intp = iA | (iB << 16);
  int xpar = x[base + 15 + grp] * 17;                // level-4 parent obs
  int tl = tid & 63;
  int topx = x[base + (tl < 15 ? tl : 0)];           // x[0..14] in wave lanes

  // ---- SP softmax ----
  float s0 = lSP[g], s1 = lSP[G_ + g];
  float sm = fmaxf(s0, s1);
  float e0 = __expf(s0 - sm), e1 = __expf(s1 - sm);
  float inv = RCP(e0 + e1);
  const float SP0 = e0 * inv, SP1 = e1 * inv;

  // ---- A softmax over axis 0 (lanes = a), column b = grp ----
  #pragma unroll
  for (int l = 0; l < 2; ++l) {
    float v = lA[a * 256 + grp * 16 + l * 8 + g];
    float m = grpmax16(v);
    float e = __expf(v - m);
    float s = grpsum16(e);
    sA[(l * 16 + grp) * 16 + a] = e * RCP(s);
  }
  // ---- Pi softmax over axis 0 ----
  if (grp < 2) {
    float v = lPi[a * 16 + grp * 8 + g];
    float m = grpmax16(v);
    float e = __expf(v - m);
    float s = grpsum16(e);
    sPi[grp * 16 + a] = e * RCP(s);
  }
  // ---- B softmax over axis 1 (M): row c = grp, lane a covers m = a+16k ----
  {
    const int c = grp;
    float vv[16];
    float mx = -1e30f;
    #pragma unroll
    for (int k = 0; k < 16; ++k) {
      vv[k] = lB[c * (256 * G_) + (a + 16 * k) * G_ + g];
      mx = fmaxf(mx, vv[k]);
    }
    mx = grpmax16(mx);
    float ssum = 0.f;
    #pragma unroll
    for (int k = 0; k < 16; ++k) { vv[k] = __expf(vv[k] - mx); ssum += vv[k]; }
    ssum = grpsum16(ssum);
    float is = RCP(ssum);
    #pragma unroll
    for (int k = 0; k < 16; ++k) sB[(a + 16 * k) * 17 + c] = vv[k] * is;
  }
  __syncthreads();

  // ---- per-lane rotated weight vectors: w[r] = A[a][(a-r)&15][l] * SP[l] ----
  f16v w0, w1;
  #pragma unroll
  for (int r = 0; r < 16; ++r) {
    int b = (a - r) & 15;
    w0[r] = sA[b * 16 + a] * SP0;
    w1[r] = sA[(16 + b) * 16 + a] * SP1;
  }
  const float pi0 = sPi[a], pi1 = sPi[16 + a];
  const float* sBa = sB + a;

  // ---- leaf gathers, pipelined up front; leaves stay raw (Pi*B) ----
  f16v lfx, lfy;
  #pragma unroll
  for (int j = 0; j < 16; ++j) {
    int xp = __shfl(leafp, j, 16);
    float pi = (j & 1) ? pi1 : pi0;
    lfx[j] = pi * sBa[xp & 0xFFFF];
    lfy[j] = pi * sBa[((unsigned)xp) >> 16];
  }

  float2 ll = {0.f, 0.f};
  float2 raw5;
  evalN<0, 0>(sBa, w0, w1, lfx, lfy, intp, ll, raw5);

  // ---- in-chain level-4 parent: reduce both subtree roots, rcp-combine ----
  {
    float n5x, n5y;
    grpsum2(raw5.x, raw5.y, n5x, n5y);
    float r5x = RCP(n5x), r5y = RCP(n5y);
    float bvP = sBa[xpar];
    float dL, dR;
    dot2f(raw5.x, raw5.y, w0, w1, dL, dR);
    float praw = fmaf(dL, r5x, dR * r5y) * bvP;
    float nup = grpsum16(praw);
    ll.x += __log2f(n5x * n5y * nup);   // triple-paired log, >= ~1e-18
    roots[grp * 17 + a] = praw * RCP(nup);
  }
  __syncthreads();

  // ---- top 15 nodes (levels 3..0) ----
  float llt = 0.f;
  topStep<true >(roots, topA, 8, 3, sB, w0, w1, a, grp, topx, llt);
  topStep<true >(topA, topB, 4, 2, sB, w0, w1, a, grp, topx, llt);
  topStep<true >(topB, topA, 2, 1, sB, w0, w1, a, grp, topx, llt);
  topStep<false>(topA, nullptr, 1, 0, sB, w0, w1, a, grp, topx, llt);

  // ---- block reduce; scale: x16 lane duplication and log2 -> ln ----
  float v = ll.x + ll.y + llt;
  #pragma unroll
  for (int off = 32; off > 0; off >>= 1) v += __shfl_down(v, off, 64);
  if ((tid & 63) == 0) red[tid >> 6] = v;
  __syncthreads();
  if (tid == 0)
    out[bid] = (red[0] + red[1] + red[2] + red[3]) * (0.6931471805599453f / 16.f);
}

extern "C" void kernel_launch(void* const* d_in, const int* in_sizes, int n_in,
                              void* d_out, int out_size, void* d_ws, size_t ws_size,
                              hipStream_t stream) {
  const float* lA  = (const float*)d_in[0];
  const float* lB  = (const float*)d_in[1];
  const float* lPi = (const float*)d_in[2];
  const float* lSP = (const float*)d_in[3];
  const int*   x   = (const int*)d_in[4];
  float* out = (float*)d_out;
  htmm_fwd_kernel<<<dim3(NT_ * G_), dim3(256), 0, stream>>>(lA, lB, lPi, lSP, x, out);
}

// Round 12
// 26.897 us; speedup vs baseline: 1.1082x; 1.1082x over previous
//
#include <hip/hip_runtime.h>

// Bottom-up HTMM forward. One block per (tree, generator); 16 groups of 16
// lanes. Group grp evaluates sibling subtrees {2grp,2grp+1} as one float2
// register chain, finishing with their level-4 parent in-chain. 16x16 matvec
// via hand-fused v_fmac_f32_dpp (row_ror); reductions via v_add_f32_dpp.
// Nodes return RAW beliefs; parent batches both children's reduce in ONE
// grpsum4, logs log2(nuL*nuR), rcp-combines. DELTA3 B-gathers hoisted into
// the leaf-gather pipeline; co-resident blocks de-locksteped via s_sleep.
#define G_   8
#define NT_  128
#define NPT_ 1023

typedef float f16v __attribute__((ext_vector_type(16)));
typedef float f8v  __attribute__((ext_vector_type(8)));
#define RCP(x) __builtin_amdgcn_rcpf(x)

// lane i receives v[(i - R) & 15] within its 16-lane row (row_ror)
template<int R>
__device__ __forceinline__ float rotr16(float v) {
  return __int_as_float(__builtin_amdgcn_update_dpp(
      0, __float_as_int(v), 0x120 | R, 0xF, 0xF, true));
}
// builtin-path reduces (compiler handles DPP hazards) — prologue/top only
__device__ __forceinline__ float grpsum16(float v) {
  v += rotr16<8>(v); v += rotr16<4>(v); v += rotr16<2>(v); v += rotr16<1>(v);
  return v;
}
__device__ __forceinline__ float grpmax16(float v) {
  v = fmaxf(v, rotr16<8>(v)); v = fmaxf(v, rotr16<4>(v));
  v = fmaxf(v, rotr16<2>(v)); v = fmaxf(v, rotr16<1>(v));
  return v;
}

// ---- hot path: 4 dots with fused v_fmac_f32_dpp. Round-robin over 4
// accumulators: self-dep distance 4 >= FMA latency; s_nop 1 guards entry.
#define FMAC4_R(R) \
  asm("v_fmac_f32_dpp %0, %4, %8 row_ror:" #R " row_mask:0xf bank_mask:0xf\n\t" \
      "v_fmac_f32_dpp %1, %5, %8 row_ror:" #R " row_mask:0xf bank_mask:0xf\n\t" \
      "v_fmac_f32_dpp %2, %6, %9 row_ror:" #R " row_mask:0xf bank_mask:0xf\n\t" \
      "v_fmac_f32_dpp %3, %7, %9 row_ror:" #R " row_mask:0xf bank_mask:0xf"     \
      : "+v"(aLx), "+v"(aLy), "+v"(aRx), "+v"(aRy)                              \
      : "v"(vLx), "v"(vLy), "v"(vRx), "v"(vRy), "v"(w0[R]), "v"(w1[R]))
#define FMAC4_FIRST(R) \
  asm("s_nop 1\n\t"                                                             \
      "v_fmac_f32_dpp %0, %4, %8 row_ror:" #R " row_mask:0xf bank_mask:0xf\n\t" \
      "v_fmac_f32_dpp %1, %5, %8 row_ror:" #R " row_mask:0xf bank_mask:0xf\n\t" \
      "v_fmac_f32_dpp %2, %6, %9 row_ror:" #R " row_mask:0xf bank_mask:0xf\n\t" \
      "v_fmac_f32_dpp %3, %7, %9 row_ror:" #R " row_mask:0xf bank_mask:0xf"     \
      : "+v"(aLx), "+v"(aLy), "+v"(aRx), "+v"(aRy)                              \
      : "v"(vLx), "v"(vLy), "v"(vRx), "v"(vRy), "v"(w0[R]), "v"(w1[R]))

__device__ __forceinline__ void dot4(float vLx, float vLy, float vRx, float vRy,
                                     const f16v& w0, const f16v& w1,
                                     float& oLx, float& oLy, float& oRx, float& oRy) {
  float aLx = vLx * w0[0];
  float aLy = vLy * w0[0];
  float aRx = vRx * w1[0];
  float aRy = vRy * w1[0];
  FMAC4_FIRST(1);
  FMAC4_R(2);  FMAC4_R(3);  FMAC4_R(4);  FMAC4_R(5);
  FMAC4_R(6);  FMAC4_R(7);  FMAC4_R(8);  FMAC4_R(9);
  FMAC4_R(10); FMAC4_R(11); FMAC4_R(12); FMAC4_R(13);
  FMAC4_R(14); FMAC4_R(15);
  oLx = aLx; oLy = aLy; oRx = aRx; oRy = aRy;
}

// ---- 2 dots fused (parent node + top phase)
#define FMAC2_R(R) \
  asm("v_fmac_f32_dpp %0, %2, %4 row_ror:" #R " row_mask:0xf bank_mask:0xf\n\t" \
      "v_fmac_f32_dpp %1, %3, %5 row_ror:" #R " row_mask:0xf bank_mask:0xf"     \
      : "+v"(aL), "+v"(aR)                                                      \
      : "v"(vL), "v"(vR), "v"(w0[R]), "v"(w1[R]))
#define FMAC2_FIRST(R) \
  asm("s_nop 1\n\t"                                                             \
      "v_fmac_f32_dpp %0, %2, %4 row_ror:" #R " row_mask:0xf bank_mask:0xf\n\t" \
      "v_fmac_f32_dpp %1, %3, %5 row_ror:" #R " row_mask:0xf bank_mask:0xf"     \
      : "+v"(aL), "+v"(aR)                                                      \
      : "v"(vL), "v"(vR), "v"(w0[R]), "v"(w1[R]))

__device__ __forceinline__ void dot2f(float vL, float vR,
                                      const f16v& w0, const f16v& w1,
                                      float& oL, float& oR) {
  float aL = vL * w0[0];
  float aR = vR * w1[0];
  FMAC2_FIRST(1);
  FMAC2_R(2);  FMAC2_R(3);  FMAC2_R(4);  FMAC2_R(5);
  FMAC2_R(6);  FMAC2_R(7);  FMAC2_R(8);  FMAC2_R(9);
  FMAC2_R(10); FMAC2_R(11); FMAC2_R(12); FMAC2_R(13);
  FMAC2_R(14); FMAC2_R(15);
  oL = aL; oR = aR;
}

// dual 16-lane sum via v_add_f32_dpp; s_nops cover the same-reg
// VALU-write -> DPP-read hazard the compiler can't see.
__device__ __forceinline__ void grpsum2(float rx, float ry, float& nux, float& nuy) {
  asm("s_nop 1\n\t"
      "v_add_f32_dpp %0, %2, %2 row_ror:8 row_mask:0xf bank_mask:0xf\n\t"
      "v_add_f32_dpp %1, %3, %3 row_ror:8 row_mask:0xf bank_mask:0xf\n\t"
      "s_nop 0\n\t"
      "v_add_f32_dpp %0, %0, %0 row_ror:4 row_mask:0xf bank_mask:0xf\n\t"
      "v_add_f32_dpp %1, %1, %1 row_ror:4 row_mask:0xf bank_mask:0xf\n\t"
      "s_nop 0\n\t"
      "v_add_f32_dpp %0, %0, %0 row_ror:2 row_mask:0xf bank_mask:0xf\n\t"
      "v_add_f32_dpp %1, %1, %1 row_ror:2 row_mask:0xf bank_mask:0xf\n\t"
      "s_nop 0\n\t"
      "v_add_f32_dpp %0, %0, %0 row_ror:1 row_mask:0xf bank_mask:0xf\n\t"
      "v_add_f32_dpp %1, %1, %1 row_ror:1 row_mask:0xf bank_mask:0xf"
      : "=&v"(nux), "=&v"(nuy)
      : "v"(rx), "v"(ry));
}

// quad 16-lane sum: 4 interleaved DPP chains, round-robin distance 4;
// s_nop 1 at entry guards freshly-written inputs.
__device__ __forceinline__ void grpsum4(float r0, float r1, float r2, float r3,
                                        float& n0, float& n1, float& n2, float& n3) {
  asm("s_nop 1\n\t"
      "v_add_f32_dpp %0, %4, %4 row_ror:8 row_mask:0xf bank_mask:0xf\n\t"
      "v_add_f32_dpp %1, %5, %5 row_ror:8 row_mask:0xf bank_mask:0xf\n\t"
      "v_add_f32_dpp %2, %6, %6 row_ror:8 row_mask:0xf bank_mask:0xf\n\t"
      "v_add_f32_dpp %3, %7, %7 row_ror:8 row_mask:0xf bank_mask:0xf\n\t"
      "v_add_f32_dpp %0, %0, %0 row_ror:4 row_mask:0xf bank_mask:0xf\n\t"
      "v_add_f32_dpp %1, %1, %1 row_ror:4 row_mask:0xf bank_mask:0xf\n\t"
      "v_add_f32_dpp %2, %2, %2 row_ror:4 row_mask:0xf bank_mask:0xf\n\t"
      "v_add_f32_dpp %3, %3, %3 row_ror:4 row_mask:0xf bank_mask:0xf\n\t"
      "v_add_f32_dpp %0, %0, %0 row_ror:2 row_mask:0xf bank_mask:0xf\n\t"
      "v_add_f32_dpp %1, %1, %1 row_ror:2 row_mask:0xf bank_mask:0xf\n\t"
      "v_add_f32_dpp %2, %2, %2 row_ror:2 row_mask:0xf bank_mask:0xf\n\t"
      "v_add_f32_dpp %3, %3, %3 row_ror:2 row_mask:0xf bank_mask:0xf\n\t"
      "v_add_f32_dpp %0, %0, %0 row_ror:1 row_mask:0xf bank_mask:0xf\n\t"
      "v_add_f32_dpp %1, %1, %1 row_ror:1 row_mask:0xf bank_mask:0xf\n\t"
      "v_add_f32_dpp %2, %2, %2 row_ror:1 row_mask:0xf bank_mask:0xf\n\t"
      "v_add_f32_dpp %3, %3, %3 row_ror:1 row_mask:0xf bank_mask:0xf"
      : "=&v"(n0), "=&v"(n1), "=&v"(n2), "=&v"(n3)
      : "v"(r0), "v"(r1), "v"(r2), "v"(r3));
}

// Post-order evaluation of two sibling depth-5 subtrees (float2 .x/.y).
// Returns RAW belief; children's nus reduced HERE (one grpsum4), logged
// pairwise, rcp-folded into the combine. DELTA3 B-values pre-gathered
// (bv3x/bv3y); DELTA<3 keep the prefetch-before-descend gather.
template<int DELTA, int J>
__device__ __forceinline__ void evalN(const float* __restrict__ sBa,
                                      const f16v& w0, const f16v& w1,
                                      const f16v& lfx, const f16v& lfy,
                                      const f8v& bv3x, const f8v& bv3y,
                                      int intp, float2& ll, float2& raw) {
  float bvA, bvB;
  float2 rawL, rawR;
  if constexpr (DELTA == 3) {
    bvA = bv3x[J];
    bvB = bv3y[J];
    rawL.x = lfx[2 * J];     rawL.y = lfy[2 * J];
    rawR.x = lfx[2 * J + 1]; rawR.y = lfy[2 * J + 1];
  } else {
    // prefetch this node's B-gather before descending (hides LDS latency)
    int xp = __shfl(intp, (1 << DELTA) - 1 + J, 16);
    bvA = sBa[xp & 0xFFFF];
    bvB = sBa[((unsigned)xp) >> 16];
    evalN<DELTA + 1, 2 * J>(sBa, w0, w1, lfx, lfy, bv3x, bv3y, intp, ll, rawL);
    evalN<DELTA + 1, 2 * J + 1>(sBa, w0, w1, lfx, lfy, bv3x, bv3y, intp, ll, rawR);
  }
  float nLx, nLy, nRx, nRy;
  grpsum4(rawL.x, rawL.y, rawR.x, rawR.y, nLx, nLy, nRx, nRy);
  ll.x += __log2f(nLx * nRx);
  ll.y += __log2f(nLy * nRy);
  float rLx = RCP(nLx), rLy = RCP(nLy);
  float rRx = RCP(nRx), rRy = RCP(nRy);
  float dLx, dLy, dRx, dRy;
  dot4(rawL.x, rawL.y, rawR.x, rawR.y, w0, w1, dLx, dLy, dRx, dRy);
  raw.x = fmaf(dLx, rLx, dRx * rRx) * bvA;
  raw.y = fmaf(dLy, rLy, dRy * rRy) * bvB;
}

template<bool SYNC>
__device__ __forceinline__ void topStep(const float* __restrict__ child,
                                        float* parent, int U, int lvl,
                                        const float* __restrict__ sB,
                                        const f16v& w0, const f16v& w1,
                                        int a, int grp, int topx, float& ll) {
  int j = (grp < U) ? grp : 0;            // clamp: keep full-wave EXEC for DPP
  int node = (1 << lvl) - 1 + j;
  int xi = __shfl(topx, node, 64);
  float bval = sB[xi * 17 + a];
  float vL = child[(2 * j) * 17 + a];
  float vR = child[(2 * j + 1) * 17 + a];
  float dL, dR;
  dot2f(vL, vR, w0, w1, dL, dR);
  float bu = (dL + dR) * bval;
  float nu = grpsum16(bu);
  if (grp < U) {
    ll += __log2f(nu);
    if (parent) parent[grp * 17 + a] = bu * RCP(nu);
  }
  if constexpr (SYNC) __syncthreads();
}

__global__ __launch_bounds__(256, 4) void htmm_fwd_kernel(
    const float* __restrict__ lA,   // (16,16,2,8)
    const float* __restrict__ lB,   // (16,256,8)
    const float* __restrict__ lPi,  // (16,2,8)
    const float* __restrict__ lSP,  // (2,8)
    const int*   __restrict__ x,    // (128*1023,)
    float*       __restrict__ out)  // (128,8)
{
  __shared__ float sB[256 * 17];    // normalized B, [m][c], stride 17
  __shared__ float sA[2 * 16 * 16]; // normalized A, [l][b][a]
  __shared__ float sPi[32];         // [l][c]
  __shared__ float roots[16 * 17];  // level-4 beliefs (normalized)
  __shared__ float topA[8 * 17];
  __shared__ float topB[4 * 17];
  __shared__ float red[4];

  const int tid = threadIdx.x;
  const int bid = blockIdx.x;       // tree*8 + g
  const int T   = bid >> 3;
  const int g   = bid & 7;
  const int a   = tid & 15;
  const int grp = tid >> 4;
  const long base = (long)T * NPT_;
  const int sx = 2 * grp;           // left sibling subtree
  const int sy = 2 * grp + 1;       // right sibling subtree

  // ---- ALL global x loads first: latency hides under the softmax prologue --
  int lxA = x[base + 511 + 16 * sx + a] * 17;
  int lxB = x[base + 511 + 16 * sy + a] * 17;
  int leafp = lxA | (lxB << 16);
  int dpl = 31 - __clz(a + 1);
  int iA = (a < 15) ? x[base + ((31 + sx) << dpl) + a] * 17 : 0;
  int iB = (a < 15) ? x[base + ((31 + sy) << dpl) + a] * 17 : 0;
  int intp = iA | (iB << 16);
  int xpar = x[base + 15 + grp] * 17;                // level-4 parent obs
  int tl = tid & 63;
  int topx = x[base + (tl < 15 ? tl : 0)];           // x[0..14] in wave lanes

  // ---- SP softmax ----
  float s0 = lSP[g], s1 = lSP[G_ + g];
  float sm = fmaxf(s0, s1);
  float e0 = __expf(s0 - sm), e1 = __expf(s1 - sm);
  float inv = RCP(e0 + e1);
  const float SP0 = e0 * inv, SP1 = e1 * inv;

  // ---- A softmax over axis 0 (lanes = a), column b = grp ----
  #pragma unroll
  for (int l = 0; l < 2; ++l) {
    float v = lA[a * 256 + grp * 16 + l * 8 + g];
    float m = grpmax16(v);
    float e = __expf(v - m);
    float s = grpsum16(e);
    sA[(l * 16 + grp) * 16 + a] = e * RCP(s);
  }
  // ---- Pi softmax over axis 0 ----
  if (grp < 2) {
    float v = lPi[a * 16 + grp * 8 + g];
    float m = grpmax16(v);
    float e = __expf(v - m);
    float s = grpsum16(e);
    sPi[grp * 16 + a] = e * RCP(s);
  }
  // ---- B softmax over axis 1 (M): row c = grp, lane a covers m = a+16k ----
  {
    const int c = grp;
    float vv[16];
    float mx = -1e30f;
    #pragma unroll
    for (int k = 0; k < 16; ++k) {
      vv[k] = lB[c * (256 * G_) + (a + 16 * k) * G_ + g];
      mx = fmaxf(mx, vv[k]);
    }
    mx = grpmax16(mx);
    float ssum = 0.f;
    #pragma unroll
    for (int k = 0; k < 16; ++k) { vv[k] = __expf(vv[k] - mx); ssum += vv[k]; }
    ssum = grpsum16(ssum);
    float is = RCP(ssum);
    #pragma unroll
    for (int k = 0; k < 16; ++k) sB[(a + 16 * k) * 17 + c] = vv[k] * is;
  }
  __syncthreads();

  // ---- de-lockstep co-resident blocks: phase-shift chains by ~0..384 cy ----
  switch (bid & 3) {
    case 1: __builtin_amdgcn_s_sleep(2); break;
    case 2: __builtin_amdgcn_s_sleep(4); break;
    case 3: __builtin_amdgcn_s_sleep(6); break;
    default: break;
  }

  // ---- per-lane rotated weight vectors: w[r] = A[a][(a-r)&15][l] * SP[l] ----
  f16v w0, w1;
  #pragma unroll
  for (int r = 0; r < 16; ++r) {
    int b = (a - r) & 15;
    w0[r] = sA[b * 16 + a] * SP0;
    w1[r] = sA[(16 + b) * 16 + a] * SP1;
  }
  const float pi0 = sPi[a], pi1 = sPi[16 + a];
  const float* sBa = sB + a;

  // ---- leaf + DELTA3 B-gathers, pipelined up front (one latency footprint) --
  f16v lfx, lfy;
  f8v bv3x, bv3y;
  #pragma unroll
  for (int j = 0; j < 16; ++j) {
    int xp = __shfl(leafp, j, 16);
    float pi = (j & 1) ? pi1 : pi0;
    lfx[j] = pi * sBa[xp & 0xFFFF];
    lfy[j] = pi * sBa[((unsigned)xp) >> 16];
  }
  #pragma unroll
  for (int j = 0; j < 8; ++j) {
    int xp = __shfl(intp, 7 + j, 16);
    bv3x[j] = sBa[xp & 0xFFFF];
    bv3y[j] = sBa[((unsigned)xp) >> 16];
  }

  float2 ll = {0.f, 0.f};
  float2 raw5;
  evalN<0, 0>(sBa, w0, w1, lfx, lfy, bv3x, bv3y, intp, ll, raw5);

  // ---- in-chain level-4 parent: reduce both subtree roots, rcp-combine ----
  {
    float n5x, n5y;
    grpsum2(raw5.x, raw5.y, n5x, n5y);
    float r5x = RCP(n5x), r5y = RCP(n5y);
    float bvP = sBa[xpar];
    float dL, dR;
    dot2f(raw5.x, raw5.y, w0, w1, dL, dR);
    float praw = fmaf(dL, r5x, dR * r5y) * bvP;
    float nup = grpsum16(praw);
    ll.x += __log2f(n5x * n5y * nup);   // triple-paired log, >= ~1e-18
    roots[grp * 17 + a] = praw * RCP(nup);
  }
  __syncthreads();

  // ---- top 15 nodes (levels 3..0) ----
  float llt = 0.f;
  topStep<true >(roots, topA, 8, 3, sB, w0, w1, a, grp, topx, llt);
  topStep<true >(topA, topB, 4, 2, sB, w0, w1, a, grp, topx, llt);
  topStep<true >(topB, topA, 2, 1, sB, w0, w1, a, grp, topx, llt);
  topStep<false>(topA, nullptr, 1, 0, sB, w0, w1, a, grp, topx, llt);

  // ---- block reduce; scale: x16 lane duplication and log2 -> ln ----
  float v = ll.x + ll.y + llt;
  #pragma unroll
  for (int off = 32; off > 0; off >>= 1) v += __shfl_down(v, off, 64);
  if ((tid & 63) == 0) red[tid >> 6] = v;
  __syncthreads();
  if (tid == 0)
    out[bid] = (red[0] + red[1] + red[2] + red[3]) * (0.6931471805599453f / 16.f);
}

extern "C" void kernel_launch(void* const* d_in, const int* in_sizes, int n_in,
                              void* d_out, int out_size, void* d_ws, size_t ws_size,
                              hipStream_t stream) {
  const float* lA  = (const float*)d_in[0];
  const float* lB  = (const float*)d_in[1];
  const float* lPi = (const float*)d_in[2];
  const float* lSP = (const float*)d_in[3];
  const int*   x   = (const int*)d_in[4];
  float* out = (float*)d_out;
  htmm_fwd_kernel<<<dim3(NT_ * G_), dim3(256), 0, stream>>>(lA, lB, lPi, lSP, x, out);
}

// Round 13
// 24.405 us; speedup vs baseline: 1.2214x; 1.1021x over previous
//
#include <hip/hip_runtime.h>

// Bottom-up HTMM forward. One block per (tree, generator); 16 groups of 16
// lanes. Group grp evaluates sibling subtrees {2grp,2grp+1} as one float2
// register chain, finishing with their level-4 parent in-chain.
// 16x16 matvec via v_dot2c_f32_f16 with fused DPP row_ror (2 MACs/instr):
// beliefs normalized (fp32 nu) then packed as f16 pairs (val[a],val[a+1]);
// weights pre-packed per lane. Reductions via v_add_f32_dpp.
#define G_   8
#define NT_  128
#define NPT_ 1023

typedef float f16v __attribute__((ext_vector_type(16)));
typedef float f8vf __attribute__((ext_vector_type(8)));
#define RCP(x) __builtin_amdgcn_rcpf(x)

// lane i receives v[(i - R) & 15] within its 16-lane row (row_ror)
template<int R>
__device__ __forceinline__ float rotr16(float v) {
  return __int_as_float(__builtin_amdgcn_update_dpp(
      0, __float_as_int(v), 0x120 | R, 0xF, 0xF, true));
}
// builtin-path reduces (compiler handles DPP hazards) — prologue/top only
__device__ __forceinline__ float grpsum16(float v) {
  v += rotr16<8>(v); v += rotr16<4>(v); v += rotr16<2>(v); v += rotr16<1>(v);
  return v;
}
__device__ __forceinline__ float grpmax16(float v) {
  v = fmaxf(v, rotr16<8>(v)); v = fmaxf(v, rotr16<4>(v));
  v = fmaxf(v, rotr16<2>(v)); v = fmaxf(v, rotr16<1>(v));
  return v;
}

// pack normalized belief as f16 pair (val[a], val[a+1]); rcp is group-uniform
__device__ __forceinline__ float packnorm(float raw, float rcp) {
  float nb = rotr16<15>(raw);           // lane a gets raw[(a+1)&15]
  float lo = raw * rcp, hi = nb * rcp;
  float pk;
  asm("v_cvt_pkrtz_f16_f32 %0, %1, %2" : "=v"(pk) : "v"(lo), "v"(hi));
  return pk;
}
// pack an already-normalized value
__device__ __forceinline__ float pack1(float v) {
  float nb = rotr16<15>(v);
  float pk;
  asm("v_cvt_pkrtz_f16_f32 %0, %1, %2" : "=v"(pk) : "v"(v), "v"(nb));
  return pk;
}

// ---- hot dot: 4 dots (L/R x float2) over packed f16 beliefs.
// out[a] = sum_t dot2(rot_{2t}(p), wpk[t]); 32 dot2c, round-robin distance 4.
__device__ __forceinline__ void dot32(float pLx, float pLy, float pRx, float pRy,
                                      const f8vf& w0, const f8vf& w1,
                                      float& tx, float& ty) {
  float aLx = 0.f, aLy = 0.f, aRx = 0.f, aRy = 0.f;
  asm("s_nop 1\n\t"
      "v_dot2c_f32_f16 %0, %4, %8\n\t"
      "v_dot2c_f32_f16 %1, %5, %8\n\t"
      "v_dot2c_f32_f16 %2, %6, %16\n\t"
      "v_dot2c_f32_f16 %3, %7, %16\n\t"
      "v_dot2c_f32_f16 %0, %4, %9 row_ror:2 row_mask:0xf bank_mask:0xf\n\t"
      "v_dot2c_f32_f16 %1, %5, %9 row_ror:2 row_mask:0xf bank_mask:0xf\n\t"
      "v_dot2c_f32_f16 %2, %6, %17 row_ror:2 row_mask:0xf bank_mask:0xf\n\t"
      "v_dot2c_f32_f16 %3, %7, %17 row_ror:2 row_mask:0xf bank_mask:0xf\n\t"
      "v_dot2c_f32_f16 %0, %4, %10 row_ror:4 row_mask:0xf bank_mask:0xf\n\t"
      "v_dot2c_f32_f16 %1, %5, %10 row_ror:4 row_mask:0xf bank_mask:0xf\n\t"
      "v_dot2c_f32_f16 %2, %6, %18 row_ror:4 row_mask:0xf bank_mask:0xf\n\t"
      "v_dot2c_f32_f16 %3, %7, %18 row_ror:4 row_mask:0xf bank_mask:0xf\n\t"
      "v_dot2c_f32_f16 %0, %4, %11 row_ror:6 row_mask:0xf bank_mask:0xf\n\t"
      "v_dot2c_f32_f16 %1, %5, %11 row_ror:6 row_mask:0xf bank_mask:0xf\n\t"
      "v_dot2c_f32_f16 %2, %6, %19 row_ror:6 row_mask:0xf bank_mask:0xf\n\t"
      "v_dot2c_f32_f16 %3, %7, %19 row_ror:6 row_mask:0xf bank_mask:0xf\n\t"
      "v_dot2c_f32_f16 %0, %4, %12 row_ror:8 row_mask:0xf bank_mask:0xf\n\t"
      "v_dot2c_f32_f16 %1, %5, %12 row_ror:8 row_mask:0xf bank_mask:0xf\n\t"
      "v_dot2c_f32_f16 %2, %6, %20 row_ror:8 row_mask:0xf bank_mask:0xf\n\t"
      "v_dot2c_f32_f16 %3, %7, %20 row_ror:8 row_mask:0xf bank_mask:0xf\n\t"
      "v_dot2c_f32_f16 %0, %4, %13 row_ror:10 row_mask:0xf bank_mask:0xf\n\t"
      "v_dot2c_f32_f16 %1, %5, %13 row_ror:10 row_mask:0xf bank_mask:0xf\n\t"
      "v_dot2c_f32_f16 %2, %6, %21 row_ror:10 row_mask:0xf bank_mask:0xf\n\t"
      "v_dot2c_f32_f16 %3, %7, %21 row_ror:10 row_mask:0xf bank_mask:0xf\n\t"
      "v_dot2c_f32_f16 %0, %4, %14 row_ror:12 row_mask:0xf bank_mask:0xf\n\t"
      "v_dot2c_f32_f16 %1, %5, %14 row_ror:12 row_mask:0xf bank_mask:0xf\n\t"
      "v_dot2c_f32_f16 %2, %6, %22 row_ror:12 row_mask:0xf bank_mask:0xf\n\t"
      "v_dot2c_f32_f16 %3, %7, %22 row_ror:12 row_mask:0xf bank_mask:0xf\n\t"
      "v_dot2c_f32_f16 %0, %4, %15 row_ror:14 row_mask:0xf bank_mask:0xf\n\t"
      "v_dot2c_f32_f16 %1, %5, %15 row_ror:14 row_mask:0xf bank_mask:0xf\n\t"
      "v_dot2c_f32_f16 %2, %6, %23 row_ror:14 row_mask:0xf bank_mask:0xf\n\t"
      "v_dot2c_f32_f16 %3, %7, %23 row_ror:14 row_mask:0xf bank_mask:0xf"
      : "+v"(aLx), "+v"(aLy), "+v"(aRx), "+v"(aRy)
      : "v"(pLx), "v"(pLy), "v"(pRx), "v"(pRy),
        "v"(w0[0]), "v"(w0[1]), "v"(w0[2]), "v"(w0[3]),
        "v"(w0[4]), "v"(w0[5]), "v"(w0[6]), "v"(w0[7]),
        "v"(w1[0]), "v"(w1[1]), "v"(w1[2]), "v"(w1[3]),
        "v"(w1[4]), "v"(w1[5]), "v"(w1[6]), "v"(w1[7]));
  tx = aLx + aRx;
  ty = aLy + aRy;
}

// single-output dot: t = W0.pL + W1.pR (level-4 parent + top phase)
__device__ __forceinline__ float dot16p(float pL, float pR,
                                        const f8vf& w0, const f8vf& w1) {
  float aL = 0.f, aR = 0.f;
  asm("s_nop 1\n\t"
      "v_dot2c_f32_f16 %0, %2, %4\n\t"
      "v_dot2c_f32_f16 %1, %3, %12\n\t"
      "v_dot2c_f32_f16 %0, %2, %5 row_ror:2 row_mask:0xf bank_mask:0xf\n\t"
      "v_dot2c_f32_f16 %1, %3, %13 row_ror:2 row_mask:0xf bank_mask:0xf\n\t"
      "v_dot2c_f32_f16 %0, %2, %6 row_ror:4 row_mask:0xf bank_mask:0xf\n\t"
      "v_dot2c_f32_f16 %1, %3, %14 row_ror:4 row_mask:0xf bank_mask:0xf\n\t"
      "v_dot2c_f32_f16 %0, %2, %7 row_ror:6 row_mask:0xf bank_mask:0xf\n\t"
      "v_dot2c_f32_f16 %1, %3, %15 row_ror:6 row_mask:0xf bank_mask:0xf\n\t"
      "v_dot2c_f32_f16 %0, %2, %8 row_ror:8 row_mask:0xf bank_mask:0xf\n\t"
      "v_dot2c_f32_f16 %1, %3, %16 row_ror:8 row_mask:0xf bank_mask:0xf\n\t"
      "v_dot2c_f32_f16 %0, %2, %9 row_ror:10 row_mask:0xf bank_mask:0xf\n\t"
      "v_dot2c_f32_f16 %1, %3, %17 row_ror:10 row_mask:0xf bank_mask:0xf\n\t"
      "v_dot2c_f32_f16 %0, %2, %10 row_ror:12 row_mask:0xf bank_mask:0xf\n\t"
      "v_dot2c_f32_f16 %1, %3, %18 row_ror:12 row_mask:0xf bank_mask:0xf\n\t"
      "v_dot2c_f32_f16 %0, %2, %11 row_ror:14 row_mask:0xf bank_mask:0xf\n\t"
      "v_dot2c_f32_f16 %1, %3, %19 row_ror:14 row_mask:0xf bank_mask:0xf"
      : "+v"(aL), "+v"(aR)
      : "v"(pL), "v"(pR),
        "v"(w0[0]), "v"(w0[1]), "v"(w0[2]), "v"(w0[3]),
        "v"(w0[4]), "v"(w0[5]), "v"(w0[6]), "v"(w0[7]),
        "v"(w1[0]), "v"(w1[1]), "v"(w1[2]), "v"(w1[3]),
        "v"(w1[4]), "v"(w1[5]), "v"(w1[6]), "v"(w1[7]));
  return aL + aR;
}

// dual 16-lane sum via v_add_f32_dpp (hazard nops for same-reg dep chains)
__device__ __forceinline__ void grpsum2(float rx, float ry, float& nux, float& nuy) {
  asm("s_nop 1\n\t"
      "v_add_f32_dpp %0, %2, %2 row_ror:8 row_mask:0xf bank_mask:0xf\n\t"
      "v_add_f32_dpp %1, %3, %3 row_ror:8 row_mask:0xf bank_mask:0xf\n\t"
      "s_nop 0\n\t"
      "v_add_f32_dpp %0, %0, %0 row_ror:4 row_mask:0xf bank_mask:0xf\n\t"
      "v_add_f32_dpp %1, %1, %1 row_ror:4 row_mask:0xf bank_mask:0xf\n\t"
      "s_nop 0\n\t"
      "v_add_f32_dpp %0, %0, %0 row_ror:2 row_mask:0xf bank_mask:0xf\n\t"
      "v_add_f32_dpp %1, %1, %1 row_ror:2 row_mask:0xf bank_mask:0xf\n\t"
      "s_nop 0\n\t"
      "v_add_f32_dpp %0, %0, %0 row_ror:1 row_mask:0xf bank_mask:0xf\n\t"
      "v_add_f32_dpp %1, %1, %1 row_ror:1 row_mask:0xf bank_mask:0xf"
      : "=&v"(nux), "=&v"(nuy)
      : "v"(rx), "v"(ry));
}

// quad 16-lane sum: 4 interleaved DPP chains, round-robin distance 4
__device__ __forceinline__ void grpsum4(float r0, float r1, float r2, float r3,
                                        float& n0, float& n1, float& n2, float& n3) {
  asm("s_nop 1\n\t"
      "v_add_f32_dpp %0, %4, %4 row_ror:8 row_mask:0xf bank_mask:0xf\n\t"
      "v_add_f32_dpp %1, %5, %5 row_ror:8 row_mask:0xf bank_mask:0xf\n\t"
      "v_add_f32_dpp %2, %6, %6 row_ror:8 row_mask:0xf bank_mask:0xf\n\t"
      "v_add_f32_dpp %3, %7, %7 row_ror:8 row_mask:0xf bank_mask:0xf\n\t"
      "v_add_f32_dpp %0, %0, %0 row_ror:4 row_mask:0xf bank_mask:0xf\n\t"
      "v_add_f32_dpp %1, %1, %1 row_ror:4 row_mask:0xf bank_mask:0xf\n\t"
      "v_add_f32_dpp %2, %2, %2 row_ror:4 row_mask:0xf bank_mask:0xf\n\t"
      "v_add_f32_dpp %3, %3, %3 row_ror:4 row_mask:0xf bank_mask:0xf\n\t"
      "v_add_f32_dpp %0, %0, %0 row_ror:2 row_mask:0xf bank_mask:0xf\n\t"
      "v_add_f32_dpp %1, %1, %1 row_ror:2 row_mask:0xf bank_mask:0xf\n\t"
      "v_add_f32_dpp %2, %2, %2 row_ror:2 row_mask:0xf bank_mask:0xf\n\t"
      "v_add_f32_dpp %3, %3, %3 row_ror:2 row_mask:0xf bank_mask:0xf\n\t"
      "v_add_f32_dpp %0, %0, %0 row_ror:1 row_mask:0xf bank_mask:0xf\n\t"
      "v_add_f32_dpp %1, %1, %1 row_ror:1 row_mask:0xf bank_mask:0xf\n\t"
      "v_add_f32_dpp %2, %2, %2 row_ror:1 row_mask:0xf bank_mask:0xf\n\t"
      "v_add_f32_dpp %3, %3, %3 row_ror:1 row_mask:0xf bank_mask:0xf"
      : "=&v"(n0), "=&v"(n1), "=&v"(n2), "=&v"(n3)
      : "v"(r0), "v"(r1), "v"(r2), "v"(r3));
}

// Post-order evaluation of two sibling depth-5 subtrees (float2 .x/.y).
// Returns RAW belief (fp32). Children reduced HERE (one grpsum4), one merged
// log, normalized+packed to f16 pairs, then 32 fused dot2c.
template<int DELTA, int J>
__device__ __forceinline__ void evalN(const float* __restrict__ sBa,
                                      const f8vf& w0, const f8vf& w1,
                                      const f16v& lfx, const f16v& lfy,
                                      int intp, float& ll, float2& raw) {
  // prefetch this node's B-gather before descending (hides LDS latency)
  int xp = __shfl(intp, (1 << DELTA) - 1 + J, 16);
  float bvA = sBa[xp & 0xFFFF];
  float bvB = sBa[((unsigned)xp) >> 16];
  float2 rawL, rawR;
  if constexpr (DELTA == 3) {
    rawL.x = lfx[2 * J];     rawL.y = lfy[2 * J];
    rawR.x = lfx[2 * J + 1]; rawR.y = lfy[2 * J + 1];
  } else {
    evalN<DELTA + 1, 2 * J>(sBa, w0, w1, lfx, lfy, intp, ll, rawL);
    evalN<DELTA + 1, 2 * J + 1>(sBa, w0, w1, lfx, lfy, intp, ll, rawR);
  }
  float nLx, nLy, nRx, nRy;
  grpsum4(rawL.x, rawL.y, rawR.x, rawR.y, nLx, nLy, nRx, nRy);
  ll += __log2f((nLx * nLy) * (nRx * nRy));   // merged: >= ~1e-28, fp32 ok
  float pLx = packnorm(rawL.x, RCP(nLx));
  float pLy = packnorm(rawL.y, RCP(nLy));
  float pRx = packnorm(rawR.x, RCP(nRx));
  float pRy = packnorm(rawR.y, RCP(nRy));
  float tx, ty;
  dot32(pLx, pLy, pRx, pRy, w0, w1, tx, ty);
  raw.x = tx * bvA;
  raw.y = ty * bvB;
}

template<bool SYNC>
__device__ __forceinline__ void topStep(const float* __restrict__ child,
                                        float* parent, int U, int lvl,
                                        const float* __restrict__ sB,
                                        const f8vf& w0, const f8vf& w1,
                                        int a, int grp, int topx, float& ll) {
  int j = (grp < U) ? grp : 0;            // clamp: keep full-wave EXEC for DPP
  int node = (1 << lvl) - 1 + j;
  int xi = __shfl(topx, node, 64);
  float bval = sB[xi * 17 + a];
  float vL = child[(2 * j) * 17 + a];     // already normalized
  float vR = child[(2 * j + 1) * 17 + a];
  float pL = pack1(vL), pR = pack1(vR);
  float t = dot16p(pL, pR, w0, w1);
  float bu = t * bval;
  float nu = grpsum16(bu);
  if (grp < U) {
    ll += __log2f(nu);
    if (parent) parent[grp * 17 + a] = bu * RCP(nu);
  }
  if constexpr (SYNC) __syncthreads();
}

__global__ __launch_bounds__(256, 4) void htmm_fwd_kernel(
    const float* __restrict__ lA,   // (16,16,2,8)
    const float* __restrict__ lB,   // (16,256,8)
    const float* __restrict__ lPi,  // (16,2,8)
    const float* __restrict__ lSP,  // (2,8)
    const int*   __restrict__ x,    // (128*1023,)
    float*       __restrict__ out)  // (128,8)
{
  __shared__ float sB[256 * 17];    // normalized B, [m][c], stride 17
  __shared__ float sA[2 * 16 * 16]; // normalized A, [l][b][a]
  __shared__ float sPi[32];         // [l][c]
  __shared__ float roots[16 * 17];  // level-4 beliefs (normalized)
  __shared__ float topA[8 * 17];
  __shared__ float topB[4 * 17];
  __shared__ float red[4];

  const int tid = threadIdx.x;
  const int bid = blockIdx.x;       // tree*8 + g
  const int T   = bid >> 3;
  const int g   = bid & 7;
  const int a   = tid & 15;
  const int grp = tid >> 4;
  const long base = (long)T * NPT_;
  const int sx = 2 * grp;           // left sibling subtree
  const int sy = 2 * grp + 1;       // right sibling subtree

  // ---- ALL global x loads first: latency hides under the softmax prologue --
  int lxA = x[base + 511 + 16 * sx + a] * 17;
  int lxB = x[base + 511 + 16 * sy + a] * 17;
  int leafp = lxA | (lxB << 16);
  int dpl = 31 - __clz(a + 1);
  int iA = (a < 15) ? x[base + ((31 + sx) << dpl) + a] * 17 : 0;
  int iB = (a < 15) ? x[base + ((31 + sy) << dpl) + a] * 17 : 0;
  int intp = iA | (iB << 16);
  int xpar = x[base + 15 + grp] * 17;                // level-4 parent obs
  int tl = tid & 63;
  int topx = x[base + (tl < 15 ? tl : 0)];           // x[0..14] in wave lanes

  // ---- SP softmax ----
  float s0 = lSP[g], s1 = lSP[G_ + g];
  float sm = fmaxf(s0, s1);
  float e0 = __expf(s0 - sm), e1 = __expf(s1 - sm);
  float inv = RCP(e0 + e1);
  const float SP0 = e0 * inv, SP1 = e1 * inv;

  // ---- A softmax over axis 0 (lanes = a), column b = grp ----
  #pragma unroll
  for (int l = 0; l < 2; ++l) {
    float v = lA[a * 256 + grp * 16 + l * 8 + g];
    float m = grpmax16(v);
    float e = __expf(v - m);
    float s = grpsum16(e);
    sA[(l * 16 + grp) * 16 + a] = e * RCP(s);
  }
  // ---- Pi softmax over axis 0 ----
  if (grp < 2) {
    float v = lPi[a * 16 + grp * 8 + g];
    float m = grpmax16(v);
    float e = __expf(v - m);
    float s = grpsum16(e);
    sPi[grp * 16 + a] = e * RCP(s);
  }
  // ---- B softmax over axis 1 (M): row c = grp, lane a covers m = a+16k ----
  {
    const int c = grp;
    float vv[16];
    float mx = -1e30f;
    #pragma unroll
    for (int k = 0; k < 16; ++k) {
      vv[k] = lB[c * (256 * G_) + (a + 16 * k) * G_ + g];
      mx = fmaxf(mx, vv[k]);
    }
    mx = grpmax16(mx);
    float ssum = 0.f;
    #pragma unroll
    for (int k = 0; k < 16; ++k) { vv[k] = __expf(vv[k] - mx); ssum += vv[k]; }
    ssum = grpsum16(ssum);
    float is = RCP(ssum);
    #pragma unroll
    for (int k = 0; k < 16; ++k) sB[(a + 16 * k) * 17 + c] = vv[k] * is;
  }
  __syncthreads();

  // ---- packed weight pairs: wpk[t] = f16(W[a][(a-2t)&15], W[a][(a-2t+1)&15])
  f8vf wpk0, wpk1;
  #pragma unroll
  for (int t = 0; t < 8; ++t) {
    int b0 = (a - 2 * t) & 15, b1 = (b0 + 1) & 15;
    float l0 = sA[b0 * 16 + a] * SP0, h0 = sA[b1 * 16 + a] * SP0;
    float l1 = sA[(16 + b0) * 16 + a] * SP1, h1 = sA[(16 + b1) * 16 + a] * SP1;
    float pk0, pk1;
    asm("v_cvt_pkrtz_f16_f32 %0, %1, %2" : "=v"(pk0) : "v"(l0), "v"(h0));
    asm("v_cvt_pkrtz_f16_f32 %0, %1, %2" : "=v"(pk1) : "v"(l1), "v"(h1));
    wpk0[t] = pk0;
    wpk1[t] = pk1;
  }
  const float pi0 = sPi[a], pi1 = sPi[16 + a];
  const float* sBa = sB + a;

  // ---- leaf gathers, pipelined up front; leaves stay raw (Pi*B, fp32) ----
  f16v lfx, lfy;
  #pragma unroll
  for (int j = 0; j < 16; ++j) {
    int xp = __shfl(leafp, j, 16);
    float pi = (j & 1) ? pi1 : pi0;
    lfx[j] = pi * sBa[xp & 0xFFFF];
    lfy[j] = pi * sBa[((unsigned)xp) >> 16];
  }

  float ll = 0.f;
  float2 raw5;
  evalN<0, 0>(sBa, wpk0, wpk1, lfx, lfy, intp, ll, raw5);

  // ---- in-chain level-4 parent: reduce both subtree roots, pack, dot ----
  {
    float n5x, n5y;
    grpsum2(raw5.x, raw5.y, n5x, n5y);
    float px = packnorm(raw5.x, RCP(n5x));
    float py = packnorm(raw5.y, RCP(n5y));
    float bvP = sBa[xpar];
    float t = dot16p(px, py, wpk0, wpk1);
    float praw = t * bvP;
    float nup = grpsum16(praw);
    ll += __log2f(n5x * n5y * nup);   // triple-paired log, >= ~1e-18
    roots[grp * 17 + a] = praw * RCP(nup);
  }
  __syncthreads();

  // ---- top 15 nodes (levels 3..0) ----
  float llt = 0.f;
  topStep<true >(roots, topA, 8, 3, sB, wpk0, wpk1, a, grp, topx, llt);
  topStep<true >(topA, topB, 4, 2, sB, wpk0, wpk1, a, grp, topx, llt);
  topStep<true >(topB, topA, 2, 1, sB, wpk0, wpk1, a, grp, topx, llt);
  topStep<false>(topA, nullptr, 1, 0, sB, wpk0, wpk1, a, grp, topx, llt);

  // ---- block reduce; scale: x16 lane duplication and log2 -> ln ----
  float v = ll + llt;
  #pragma unroll
  for (int off = 32; off > 0; off >>= 1) v += __shfl_down(v, off, 64);
  if ((tid & 63) == 0) red[tid >> 6] = v;
  __syncthreads();
  if (tid == 0)
    out[bid] = (red[0] + red[1] + red[2] + red[3]) * (0.6931471805599453f / 16.f);
}

extern "C" void kernel_launch(void* const* d_in, const int* in_sizes, int n_in,
                              void* d_out, int out_size, void* d_ws, size_t ws_size,
                              hipStream_t stream) {
  const float* lA  = (const float*)d_in[0];
  const float* lB  = (const float*)d_in[1];
  const float* lPi = (const float*)d_in[2];
  const float* lSP = (const float*)d_in[3];
  const int*   x   = (const int*)d_in[4];
  float* out = (float*)d_out;
  htmm_fwd_kernel<<<dim3(NT_ * G_), dim3(256), 0, stream>>>(lA, lB, lPi, lSP, x, out);
}

// Round 14
// 19.718 us; speedup vs baseline: 1.5117x; 1.2377x over previous
//
#include <hip/hip_runtime.h>

// Bottom-up HTMM forward, MFMA edition. Block = (tree, generator), 256 thr.
// Tree split into 64 depth-4 subtrees (levels 6..9); 4 waves x 16 MFMA
// columns, column = subtree, lockstep post-order. Per internal node ONE
// v_mfma_f32_16x16x32_f16 computes W0*uL + W1*uR for 16 columns (A = [W0|W1]
// interleaved along K per lane-group; B = concat(pkL,pkR)). Child D-layout
// == parent B-layout => no cross-lane repack. nu = 3 adds + 2 shfl_xor.
// Top 63 nodes via LDS ping-pong MFMA steps. DPP only in the prologue.
#define G_   8
#define NT_  128
#define NPT_ 1023

typedef __fp16 half8 __attribute__((ext_vector_type(8)));
typedef __fp16 half4v __attribute__((ext_vector_type(4)));
typedef float f32x4 __attribute__((ext_vector_type(4)));
#define RCP(x) __builtin_amdgcn_rcpf(x)

// lane i receives v[(i - R) & 15] within its 16-lane row (prologue reduces)
template<int R>
__device__ __forceinline__ float rotr16(float v) {
  return __int_as_float(__builtin_amdgcn_update_dpp(
      0, __float_as_int(v), 0x120 | R, 0xF, 0xF, true));
}
__device__ __forceinline__ float grpsum16(float v) {
  v += rotr16<8>(v); v += rotr16<4>(v); v += rotr16<2>(v); v += rotr16<1>(v);
  return v;
}
__device__ __forceinline__ float grpmax16(float v) {
  v = fmaxf(v, rotr16<8>(v)); v = fmaxf(v, rotr16<4>(v));
  v = fmaxf(v, rotr16<2>(v)); v = fmaxf(v, rotr16<1>(v));
  return v;
}

// all-reduce over the 4 row-group lanes of a column (n, n+16, n+32, n+48)
__device__ __forceinline__ float colsum(float s) {
  s += __shfl_xor(s, 16, 64);
  s += __shfl_xor(s, 32, 64);
  return s;
}

// leaf step: raw = Pi[m][pos] * B[m][x]; normalize per column; log nu.
__device__ __forceinline__ half4v leafstep(const float* __restrict__ sB, int m0,
                                           int xv, float p0, float p1,
                                           float p2, float p3, float& ll) {
  float r0 = sB[xv + m0 + 0] * p0;
  float r1 = sB[xv + m0 + 1] * p1;
  float r2 = sB[xv + m0 + 2] * p2;
  float r3 = sB[xv + m0 + 3] * p3;
  float nu = colsum((r0 + r1) + (r2 + r3));
  ll += __log2f(nu);
  float rc = RCP(nu);
  half4v p;
  p[0] = (__fp16)(r0 * rc); p[1] = (__fp16)(r1 * rc);
  p[2] = (__fp16)(r2 * rc); p[3] = (__fp16)(r3 * rc);
  return p;
}

// internal step: D = A*[pkL;pkR] (one MFMA), * B[m][x], normalize, log.
__device__ __forceinline__ half4v istep(const float* __restrict__ sB, int m0,
                                        int xv, half8 af, half4v pl, half4v pr,
                                        float& ll) {
  half8 bb;
  bb[0] = pl[0]; bb[1] = pl[1]; bb[2] = pl[2]; bb[3] = pl[3];
  bb[4] = pr[0]; bb[5] = pr[1]; bb[6] = pr[2]; bb[7] = pr[3];
  f32x4 z = {0.f, 0.f, 0.f, 0.f};
  f32x4 acc = __builtin_amdgcn_mfma_f32_16x16x32_f16(af, bb, z, 0, 0, 0);
  float r0 = acc[0] * sB[xv + m0 + 0];
  float r1 = acc[1] * sB[xv + m0 + 1];
  float r2 = acc[2] * sB[xv + m0 + 2];
  float r3 = acc[3] * sB[xv + m0 + 3];
  float nu = colsum((r0 + r1) + (r2 + r3));
  ll += __log2f(nu);
  float rc = RCP(nu);
  half4v p;
  p[0] = (__fp16)(r0 * rc); p[1] = (__fp16)(r1 * rc);
  p[2] = (__fp16)(r2 * rc); p[3] = (__fp16)(r3 * rc);
  return p;
}

// top-phase step: children read from LDS (fp32), result written to LDS.
__device__ __forceinline__ void topstep(const float* __restrict__ rb, int rs,
                                        float* wb, int ws, int U, int xv,
                                        const float* __restrict__ sB, int m0,
                                        int col, half8 af, float& ll) {
  bool valid = col < U;
  int tc = valid ? col : 0;
  half8 bb;
  #pragma unroll
  for (int i = 0; i < 4; ++i) {
    bb[i]     = (__fp16)rb[(m0 + i) * rs + 2 * tc];
    bb[4 + i] = (__fp16)rb[(m0 + i) * rs + 2 * tc + 1];
  }
  f32x4 z = {0.f, 0.f, 0.f, 0.f};
  f32x4 acc = __builtin_amdgcn_mfma_f32_16x16x32_f16(af, bb, z, 0, 0, 0);
  float r0 = acc[0] * sB[xv + m0 + 0];
  float r1 = acc[1] * sB[xv + m0 + 1];
  float r2 = acc[2] * sB[xv + m0 + 2];
  float r3 = acc[3] * sB[xv + m0 + 3];
  float nu = colsum((r0 + r1) + (r2 + r3));
  float rc = RCP(nu);
  if (valid) {
    ll += __log2f(nu);
    if (wb) {
      wb[(m0 + 0) * ws + col] = r0 * rc;
      wb[(m0 + 1) * ws + col] = r1 * rc;
      wb[(m0 + 2) * ws + col] = r2 * rc;
      wb[(m0 + 3) * ws + col] = r3 * rc;
    }
  }
  __syncthreads();
}

__global__ __launch_bounds__(256, 4) void htmm_fwd_kernel(
    const float* __restrict__ lA,   // (16,16,2,8)
    const float* __restrict__ lB,   // (16,256,8)
    const float* __restrict__ lPi,  // (16,2,8)
    const float* __restrict__ lSP,  // (2,8)
    const int*   __restrict__ x,    // (128*1023,)
    float*       __restrict__ out)  // (128,8)
{
  __shared__ float sB[256 * 17];    // normalized B, [m_obs][state], stride 17
  __shared__ float sA[2 * 16 * 16]; // normalized A, [l][b][a]
  __shared__ float sPi[32];         // [l][state]
  __shared__ float rootsA[16 * 65]; // [state][col<=64], ping
  __shared__ float rootsB[16 * 33]; // [state][col<=32], pong
  __shared__ float red[4];

  const int tid = threadIdx.x;
  const int bid = blockIdx.x;       // tree*8 + g
  const int T   = bid >> 3;
  const int g   = bid & 7;
  const int lane = tid & 63;
  const int wv   = tid >> 6;
  const int c    = lane & 15;       // column within wave / out-state m
  const int col  = (wv << 4) | c;   // subtree id 0..63
  const int m0   = (lane >> 4) << 2;// row base 0,4,8,12
  const int a    = tid & 15;        // prologue lane-state
  const int grp  = tid >> 4;        // prologue group
  const long base = (long)T * NPT_;

  // ---- ALL global x loads first (hide under softmax prologue) ----
  int xl[8], x8[4], x7[2], xt[6];
  #pragma unroll
  for (int j = 0; j < 8; ++j) xl[j] = x[base + 511 + 8 * col + j] * 17;
  #pragma unroll
  for (int t = 0; t < 4; ++t) x8[t] = x[base + 255 + 4 * col + t] * 17;
  #pragma unroll
  for (int t = 0; t < 2; ++t) x7[t] = x[base + 127 + 2 * col + t] * 17;
  const int x6 = x[base + 63 + col] * 17;
  #pragma unroll
  for (int lvl = 0; lvl < 6; ++lvl) {
    int U = 1 << lvl;
    int tc = (col < U) ? col : (U - 1);
    xt[lvl] = x[base + (U - 1) + tc] * 17;
  }

  // ---- SP softmax ----
  float s0 = lSP[g], s1 = lSP[G_ + g];
  float sm = fmaxf(s0, s1);
  float e0 = __expf(s0 - sm), e1 = __expf(s1 - sm);
  float inv = RCP(e0 + e1);
  const float SP0 = e0 * inv, SP1 = e1 * inv;

  // ---- A softmax over axis 0 (lanes = a), column b = grp ----
  #pragma unroll
  for (int l = 0; l < 2; ++l) {
    float v = lA[a * 256 + grp * 16 + l * 8 + g];
    float m = grpmax16(v);
    float e = __expf(v - m);
    float s = grpsum16(e);
    sA[(l * 16 + grp) * 16 + a] = e * RCP(s);
  }
  // ---- Pi softmax over axis 0 ----
  if (grp < 2) {
    float v = lPi[a * 16 + grp * 8 + g];
    float m = grpmax16(v);
    float e = __expf(v - m);
    float s = grpsum16(e);
    sPi[grp * 16 + a] = e * RCP(s);
  }
  // ---- B softmax over axis 1 (M): row c = grp, lane a covers m = a+16k ----
  {
    const int cc = grp;
    float vv[16];
    float mx = -1e30f;
    #pragma unroll
    for (int k = 0; k < 16; ++k) {
      vv[k] = lB[cc * (256 * G_) + (a + 16 * k) * G_ + g];
      mx = fmaxf(mx, vv[k]);
    }
    mx = grpmax16(mx);
    float ssum = 0.f;
    #pragma unroll
    for (int k = 0; k < 16; ++k) { vv[k] = __expf(vv[k] - mx); ssum += vv[k]; }
    ssum = grpsum16(ssum);
    float is = RCP(ssum);
    #pragma unroll
    for (int k = 0; k < 16; ++k) sB[(a + 16 * k) * 17 + cc] = vv[k] * is;
  }
  __syncthreads();

  // ---- A-fragment: af[i<4] = W0[m=c][b=m0+i], af[i>=4] = W1[m=c][b=m0+i-4]
  // (k' interleaved per lane-group so B = concat(pkL,pkR) works)
  half8 af;
  #pragma unroll
  for (int i = 0; i < 4; ++i) {
    af[i]     = (__fp16)(sA[(m0 + i) * 16 + c] * SP0);
    af[4 + i] = (__fp16)(sA[(16 + m0 + i) * 16 + c] * SP1);
  }
  // leaf Pi values for this lane's 4 rows
  const float pi00 = sPi[m0 + 0], pi01 = sPi[m0 + 1];
  const float pi02 = sPi[m0 + 2], pi03 = sPi[m0 + 3];
  const float pi10 = sPi[16 + m0 + 0], pi11 = sPi[16 + m0 + 1];
  const float pi12 = sPi[16 + m0 + 2], pi13 = sPi[16 + m0 + 3];

  float ll = 0.f;

  // ---- depth-4 subtree, post-order, all 64 columns lockstep ----
  half4v t0, t1, p80, p81, q0, q1;
  t0 = leafstep(sB, m0, xl[0], pi00, pi01, pi02, pi03, ll);
  t1 = leafstep(sB, m0, xl[1], pi10, pi11, pi12, pi13, ll);
  p80 = istep(sB, m0, x8[0], af, t0, t1, ll);
  t0 = leafstep(sB, m0, xl[2], pi00, pi01, pi02, pi03, ll);
  t1 = leafstep(sB, m0, xl[3], pi10, pi11, pi12, pi13, ll);
  p81 = istep(sB, m0, x8[1], af, t0, t1, ll);
  q0 = istep(sB, m0, x7[0], af, p80, p81, ll);
  t0 = leafstep(sB, m0, xl[4], pi00, pi01, pi02, pi03, ll);
  t1 = leafstep(sB, m0, xl[5], pi10, pi11, pi12, pi13, ll);
  p80 = istep(sB, m0, x8[2], af, t0, t1, ll);
  t0 = leafstep(sB, m0, xl[6], pi00, pi01, pi02, pi03, ll);
  t1 = leafstep(sB, m0, xl[7], pi10, pi11, pi12, pi13, ll);
  p81 = istep(sB, m0, x8[3], af, t0, t1, ll);
  q1 = istep(sB, m0, x7[1], af, p80, p81, ll);

  // ---- subtree root (level 6): store normalized fp32 to rootsA ----
  {
    half8 bb;
    bb[0] = q0[0]; bb[1] = q0[1]; bb[2] = q0[2]; bb[3] = q0[3];
    bb[4] = q1[0]; bb[5] = q1[1]; bb[6] = q1[2]; bb[7] = q1[3];
    f32x4 z = {0.f, 0.f, 0.f, 0.f};
    f32x4 acc = __builtin_amdgcn_mfma_f32_16x16x32_f16(af, bb, z, 0, 0, 0);
    float r0 = acc[0] * sB[x6 + m0 + 0];
    float r1 = acc[1] * sB[x6 + m0 + 1];
    float r2 = acc[2] * sB[x6 + m0 + 2];
    float r3 = acc[3] * sB[x6 + m0 + 3];
    float nu = colsum((r0 + r1) + (r2 + r3));
    ll += __log2f(nu);
    float rc = RCP(nu);
    rootsA[(m0 + 0) * 65 + col] = r0 * rc;
    rootsA[(m0 + 1) * 65 + col] = r1 * rc;
    rootsA[(m0 + 2) * 65 + col] = r2 * rc;
    rootsA[(m0 + 3) * 65 + col] = r3 * rc;
  }
  __syncthreads();

  // ---- top 63 nodes: levels 5..0, LDS ping-pong ----
  topstep(rootsA, 65, rootsB, 33, 32, xt[5], sB, m0, col, af, ll);
  topstep(rootsB, 33, rootsA, 65, 16, xt[4], sB, m0, col, af, ll);
  topstep(rootsA, 65, rootsB, 33,  8, xt[3], sB, m0, col, af, ll);
  topstep(rootsB, 33, rootsA, 65,  4, xt[2], sB, m0, col, af, ll);
  topstep(rootsA, 65, rootsB, 33,  2, xt[1], sB, m0, col, af, ll);
  topstep(rootsB, 33, nullptr, 0,  1, xt[0], sB, m0, col, af, ll);

  // ---- block reduce; each nu logged by 4 lane-replicas -> /4; log2 -> ln --
  float v = ll;
  #pragma unroll
  for (int off = 32; off > 0; off >>= 1) v += __shfl_down(v, off, 64);
  if (lane == 0) red[wv] = v;
  __syncthreads();
  if (tid == 0)
    out[bid] = (red[0] + red[1] + red[2] + red[3]) *
               (0.6931471805599453f * 0.25f);
}

extern "C" void kernel_launch(void* const* d_in, const int* in_sizes, int n_in,
                              void* d_out, int out_size, void* d_ws, size_t ws_size,
                              hipStream_t stream) {
  const float* lA  = (const float*)d_in[0];
  const float* lB  = (const float*)d_in[1];
  const float* lPi = (const float*)d_in[2];
  const float* lSP = (const float*)d_in[3];
  const int*   x   = (const int*)d_in[4];
  float* out = (float*)d_out;
  htmm_fwd_kernel<<<dim3(NT_ * G_), dim3(256), 0, stream>>>(lA, lB, lPi, lSP, x, out);
}

// Round 15
// 18.674 us; speedup vs baseline: 1.5962x; 1.0559x over previous
//
#include <hip/hip_runtime.h>

// Bottom-up HTMM forward, MFMA edition v2. Block = (tree, generator), 256 thr.
// 64 depth-4 subtrees (levels 6..9); 4 waves x 16 MFMA columns, lockstep
// post-order; one v_mfma_f32_16x16x32_f16 per internal node for 16 columns.
// v2: sB stride 20 -> single ds_read_b128 gather per step; colsum via
// v_permlane16/32_swap (pure VALU, no LDS); paired deferred logs.
#define G_   8
#define NT_  128
#define NPT_ 1023
#define SBS  20   // sB row stride (floats): 80B rows, 16B-aligned 4-float reads

typedef __fp16 half8 __attribute__((ext_vector_type(8)));
typedef __fp16 half4v __attribute__((ext_vector_type(4)));
typedef float f32x4 __attribute__((ext_vector_type(4)));
#define RCP(x) __builtin_amdgcn_rcpf(x)

// lane i receives v[(i - R) & 15] within its 16-lane row (prologue reduces)
template<int R>
__device__ __forceinline__ float rotr16(float v) {
  return __int_as_float(__builtin_amdgcn_update_dpp(
      0, __float_as_int(v), 0x120 | R, 0xF, 0xF, true));
}
__device__ __forceinline__ float grpsum16(float v) {
  v += rotr16<8>(v); v += rotr16<4>(v); v += rotr16<2>(v); v += rotr16<1>(v);
  return v;
}
__device__ __forceinline__ float grpmax16(float v) {
  v = fmaxf(v, rotr16<8>(v)); v = fmaxf(v, rotr16<4>(v));
  v = fmaxf(v, rotr16<2>(v)); v = fmaxf(v, rotr16<1>(v));
  return v;
}

// all-reduce over the 4 row-group lanes of a column (n, n+16, n+32, n+48):
// pure VALU via permlane swaps (s_nop covers VALU-write -> permlane-read).
__device__ __forceinline__ float colsum(float s) {
  float t = s;
  asm("s_nop 1\n\t"
      "v_permlane16_swap_b32 %0, %1" : "+v"(s), "+v"(t));
  s = s + t;                       // rows: [r0+r1, r0+r1, r2+r3, r2+r3]
  float u = s;
  asm("s_nop 1\n\t"
      "v_permlane32_swap_b32 %0, %1" : "+v"(s), "+v"(u));
  return s + u;                    // full 16-state sum in all lanes
}

// leaf step: raw = Pi[m][pos] * B[m][x]; normalize per column; RETURN nu.
__device__ __forceinline__ half4v leafstep(const float* __restrict__ sB, int m0,
                                           int xv, float p0, float p1,
                                           float p2, float p3, float& nuOut) {
  f32x4 b = *(const f32x4*)(sB + xv + m0);       // one ds_read_b128
  float r0 = b[0] * p0, r1 = b[1] * p1, r2 = b[2] * p2, r3 = b[3] * p3;
  float nu = colsum((r0 + r1) + (r2 + r3));
  nuOut = nu;
  float rc = RCP(nu);
  half4v p;
  p[0] = (__fp16)(r0 * rc); p[1] = (__fp16)(r1 * rc);
  p[2] = (__fp16)(r2 * rc); p[3] = (__fp16)(r3 * rc);
  return p;
}

// internal step: D = A*[pkL;pkR] (one MFMA) * B[m][x]; logs CHILDREN's nus
// (paired); returns own nu unlogged.
__device__ __forceinline__ half4v istep(const float* __restrict__ sB, int m0,
                                        int xv, half8 af, half4v pl, half4v pr,
                                        float nuL, float nuR,
                                        float& nuOut, float& ll) {
  half8 bb;
  bb[0] = pl[0]; bb[1] = pl[1]; bb[2] = pl[2]; bb[3] = pl[3];
  bb[4] = pr[0]; bb[5] = pr[1]; bb[6] = pr[2]; bb[7] = pr[3];
  f32x4 z = {0.f, 0.f, 0.f, 0.f};
  f32x4 acc = __builtin_amdgcn_mfma_f32_16x16x32_f16(af, bb, z, 0, 0, 0);
  ll += __log2f(nuL * nuR);                      // paired deferred log
  f32x4 b = *(const f32x4*)(sB + xv + m0);       // one ds_read_b128
  float r0 = acc[0] * b[0], r1 = acc[1] * b[1];
  float r2 = acc[2] * b[2], r3 = acc[3] * b[3];
  float nu = colsum((r0 + r1) + (r2 + r3));
  nuOut = nu;
  float rc = RCP(nu);
  half4v p;
  p[0] = (__fp16)(r0 * rc); p[1] = (__fp16)(r1 * rc);
  p[2] = (__fp16)(r2 * rc); p[3] = (__fp16)(r3 * rc);
  return p;
}

// top-phase step: children read from LDS (fp32), result written to LDS.
__device__ __forceinline__ void topstep(const float* __restrict__ rb, int rs,
                                        float* wb, int ws, int U, int xv,
                                        const float* __restrict__ sB, int m0,
                                        int col, half8 af, float& ll) {
  bool valid = col < U;
  int tc = valid ? col : 0;
  half8 bb;
  #pragma unroll
  for (int i = 0; i < 4; ++i) {
    bb[i]     = (__fp16)rb[(m0 + i) * rs + 2 * tc];
    bb[4 + i] = (__fp16)rb[(m0 + i) * rs + 2 * tc + 1];
  }
  f32x4 z = {0.f, 0.f, 0.f, 0.f};
  f32x4 acc = __builtin_amdgcn_mfma_f32_16x16x32_f16(af, bb, z, 0, 0, 0);
  f32x4 b = *(const f32x4*)(sB + xv + m0);
  float r0 = acc[0] * b[0], r1 = acc[1] * b[1];
  float r2 = acc[2] * b[2], r3 = acc[3] * b[3];
  float nu = colsum((r0 + r1) + (r2 + r3));
  float rc = RCP(nu);
  if (valid) {
    ll += __log2f(nu);
    if (wb) {
      wb[(m0 + 0) * ws + col] = r0 * rc;
      wb[(m0 + 1) * ws + col] = r1 * rc;
      wb[(m0 + 2) * ws + col] = r2 * rc;
      wb[(m0 + 3) * ws + col] = r3 * rc;
    }
  }
  __syncthreads();
}

__global__ __launch_bounds__(256, 4) void htmm_fwd_kernel(
    const float* __restrict__ lA,   // (16,16,2,8)
    const float* __restrict__ lB,   // (16,256,8)
    const float* __restrict__ lPi,  // (16,2,8)
    const float* __restrict__ lSP,  // (2,8)
    const int*   __restrict__ x,    // (128*1023,)
    float*       __restrict__ out)  // (128,8)
{
  __shared__ float sB[256 * SBS];   // normalized B, [m_obs][state], stride 20
  __shared__ float sA[2 * 16 * 16]; // normalized A, [l][b][a]
  __shared__ float sPi[32];         // [l][state]
  __shared__ float rootsA[16 * 65]; // [state][col<=64], ping
  __shared__ float rootsB[16 * 33]; // [state][col<=32], pong
  __shared__ float red[4];

  const int tid = threadIdx.x;
  const int bid = blockIdx.x;       // tree*8 + g
  const int T   = bid >> 3;
  const int g   = bid & 7;
  const int lane = tid & 63;
  const int wv   = tid >> 6;
  const int c    = lane & 15;       // column within wave / out-state m
  const int col  = (wv << 4) | c;   // subtree id 0..63
  const int m0   = (lane >> 4) << 2;// row base 0,4,8,12
  const int a    = tid & 15;        // prologue lane-state
  const int grp  = tid >> 4;        // prologue group
  const long base = (long)T * NPT_;

  // ---- ALL global x loads first (hide under softmax prologue) ----
  int xl[8], x8[4], x7[2], xt[6];
  #pragma unroll
  for (int j = 0; j < 8; ++j) xl[j] = x[base + 511 + 8 * col + j] * SBS;
  #pragma unroll
  for (int t = 0; t < 4; ++t) x8[t] = x[base + 255 + 4 * col + t] * SBS;
  #pragma unroll
  for (int t = 0; t < 2; ++t) x7[t] = x[base + 127 + 2 * col + t] * SBS;
  const int x6 = x[base + 63 + col] * SBS;
  #pragma unroll
  for (int lvl = 0; lvl < 6; ++lvl) {
    int U = 1 << lvl;
    int tc = (col < U) ? col : (U - 1);
    xt[lvl] = x[base + (U - 1) + tc] * SBS;
  }

  // ---- SP softmax ----
  float s0 = lSP[g], s1 = lSP[G_ + g];
  float sm = fmaxf(s0, s1);
  float e0 = __expf(s0 - sm), e1 = __expf(s1 - sm);
  float inv = RCP(e0 + e1);
  const float SP0 = e0 * inv, SP1 = e1 * inv;

  // ---- A softmax over axis 0 (lanes = a), column b = grp ----
  #pragma unroll
  for (int l = 0; l < 2; ++l) {
    float v = lA[a * 256 + grp * 16 + l * 8 + g];
    float m = grpmax16(v);
    float e = __expf(v - m);
    float s = grpsum16(e);
    sA[(l * 16 + grp) * 16 + a] = e * RCP(s);
  }
  // ---- Pi softmax over axis 0 ----
  if (grp < 2) {
    float v = lPi[a * 16 + grp * 8 + g];
    float m = grpmax16(v);
    float e = __expf(v - m);
    float s = grpsum16(e);
    sPi[grp * 16 + a] = e * RCP(s);
  }
  // ---- B softmax over axis 1 (M): row c = grp, lane a covers m = a+16k ----
  {
    const int cc = grp;
    float vv[16];
    float mx = -1e30f;
    #pragma unroll
    for (int k = 0; k < 16; ++k) {
      vv[k] = lB[cc * (256 * G_) + (a + 16 * k) * G_ + g];
      mx = fmaxf(mx, vv[k]);
    }
    mx = grpmax16(mx);
    float ssum = 0.f;
    #pragma unroll
    for (int k = 0; k < 16; ++k) { vv[k] = __expf(vv[k] - mx); ssum += vv[k]; }
    ssum = grpsum16(ssum);
    float is = RCP(ssum);
    #pragma unroll
    for (int k = 0; k < 16; ++k) sB[(a + 16 * k) * SBS + cc] = vv[k] * is;
  }
  __syncthreads();

  // ---- A-fragment: af[i<4] = W0[m=c][b=m0+i], af[i>=4] = W1[m=c][b=m0+i-4]
  half8 af;
  #pragma unroll
  for (int i = 0; i < 4; ++i) {
    af[i]     = (__fp16)(sA[(m0 + i) * 16 + c] * SP0);
    af[4 + i] = (__fp16)(sA[(16 + m0 + i) * 16 + c] * SP1);
  }
  // leaf Pi values for this lane's 4 rows
  const float pi00 = sPi[m0 + 0], pi01 = sPi[m0 + 1];
  const float pi02 = sPi[m0 + 2], pi03 = sPi[m0 + 3];
  const float pi10 = sPi[16 + m0 + 0], pi11 = sPi[16 + m0 + 1];
  const float pi12 = sPi[16 + m0 + 2], pi13 = sPi[16 + m0 + 3];

  float ll = 0.f;

  // ---- depth-4 subtree, post-order, all 64 columns lockstep ----
  half4v t0, t1, p80, p81, q0, q1;
  float nl0, nl1, n80, n81, n70, n71;
  t0 = leafstep(sB, m0, xl[0], pi00, pi01, pi02, pi03, nl0);
  t1 = leafstep(sB, m0, xl[1], pi10, pi11, pi12, pi13, nl1);
  p80 = istep(sB, m0, x8[0], af, t0, t1, nl0, nl1, n80, ll);
  t0 = leafstep(sB, m0, xl[2], pi00, pi01, pi02, pi03, nl0);
  t1 = leafstep(sB, m0, xl[3], pi10, pi11, pi12, pi13, nl1);
  p81 = istep(sB, m0, x8[1], af, t0, t1, nl0, nl1, n81, ll);
  q0 = istep(sB, m0, x7[0], af, p80, p81, n80, n81, n70, ll);
  t0 = leafstep(sB, m0, xl[4], pi00, pi01, pi02, pi03, nl0);
  t1 = leafstep(sB, m0, xl[5], pi10, pi11, pi12, pi13, nl1);
  p80 = istep(sB, m0, x8[2], af, t0, t1, nl0, nl1, n80, ll);
  t0 = leafstep(sB, m0, xl[6], pi00, pi01, pi02, pi03, nl0);
  t1 = leafstep(sB, m0, xl[7], pi10, pi11, pi12, pi13, nl1);
  p81 = istep(sB, m0, x8[3], af, t0, t1, nl0, nl1, n81, ll);
  q1 = istep(sB, m0, x7[1], af, p80, p81, n80, n81, n71, ll);

  // ---- subtree root (level 6): store normalized fp32 to rootsA ----
  {
    half8 bb;
    bb[0] = q0[0]; bb[1] = q0[1]; bb[2] = q0[2]; bb[3] = q0[3];
    bb[4] = q1[0]; bb[5] = q1[1]; bb[6] = q1[2]; bb[7] = q1[3];
    f32x4 z = {0.f, 0.f, 0.f, 0.f};
    f32x4 acc = __builtin_amdgcn_mfma_f32_16x16x32_f16(af, bb, z, 0, 0, 0);
    f32x4 b = *(const f32x4*)(sB + x6 + m0);
    float r0 = acc[0] * b[0], r1 = acc[1] * b[1];
    float r2 = acc[2] * b[2], r3 = acc[3] * b[3];
    float nu = colsum((r0 + r1) + (r2 + r3));
    ll += __log2f(n70 * n71 * nu);   // triple-paired log, >= ~1e-24
    float rc = RCP(nu);
    rootsA[(m0 + 0) * 65 + col] = r0 * rc;
    rootsA[(m0 + 1) * 65 + col] = r1 * rc;
    rootsA[(m0 + 2) * 65 + col] = r2 * rc;
    rootsA[(m0 + 3) * 65 + col] = r3 * rc;
  }
  __syncthreads();

  // ---- top 63 nodes: levels 5..0, LDS ping-pong ----
  topstep(rootsA, 65, rootsB, 33, 32, xt[5], sB, m0, col, af, ll);
  topstep(rootsB, 33, rootsA, 65, 16, xt[4], sB, m0, col, af, ll);
  topstep(rootsA, 65, rootsB, 33,  8, xt[3], sB, m0, col, af, ll);
  topstep(rootsB, 33, rootsA, 65,  4, xt[2], sB, m0, col, af, ll);
  topstep(rootsA, 65, rootsB, 33,  2, xt[1], sB, m0, col, af, ll);
  topstep(rootsB, 33, nullptr, 0,  1, xt[0], sB, m0, col, af, ll);

  // ---- block reduce; each nu logged by 4 lane-replicas -> /4; log2 -> ln --
  float v = ll;
  #pragma unroll
  for (int off = 32; off > 0; off >>= 1) v += __shfl_down(v, off, 64);
  if (lane == 0) red[wv] = v;
  __syncthreads();
  if (tid == 0)
    out[bid] = (red[0] + red[1] + red[2] + red[3]) *
               (0.6931471805599453f * 0.25f);
}

extern "C" void kernel_launch(void* const* d_in, const int* in_sizes, int n_in,
                              void* d_out, int out_size, void* d_ws, size_t ws_size,
                              hipStream_t stream) {
  const float* lA  = (const float*)d_in[0];
  const float* lB  = (const float*)d_in[1];
  const float* lPi = (const float*)d_in[2];
  const float* lSP = (const float*)d_in[3];
  const int*   x   = (const int*)d_in[4];
  float* out = (float*)d_out;
  htmm_fwd_kernel<<<dim3(NT_ * G_), dim3(256), 0, stream>>>(lA, lB, lPi, lSP, x, out);
}

// Round 16
// 18.457 us; speedup vs baseline: 1.6150x; 1.0118x over previous
//
#include <hip/hip_runtime.h>

// Bottom-up HTMM forward, MFMA edition v3. Block = (tree, generator), 256 thr.
// 64 depth-4 subtrees (levels 6..9); 4 waves x 16 MFMA columns, lockstep
// post-order; one v_mfma_f32_16x16x32_f16 per internal node for 16 columns.
// v3: x staged to LDS via coalesced loads (scattered index reads now LDS);
// top levels 5..2 computed intra-wave via shfl (no barriers, no LDS ping-
// pong) -- only levels 1,0 use LDS+barrier. colsum via permlane swaps.
#define G_   8
#define NT_  128
#define NPT_ 1023
#define SBS  20   // sB row stride (floats): 80B rows, 16B-aligned 4-float reads

typedef __fp16 half8 __attribute__((ext_vector_type(8)));
typedef __fp16 half4v __attribute__((ext_vector_type(4)));
typedef float f32x4 __attribute__((ext_vector_type(4)));
#define RCP(x) __builtin_amdgcn_rcpf(x)

// lane i receives v[(i - R) & 15] within its 16-lane row (prologue reduces)
template<int R>
__device__ __forceinline__ float rotr16(float v) {
  return __int_as_float(__builtin_amdgcn_update_dpp(
      0, __float_as_int(v), 0x120 | R, 0xF, 0xF, true));
}
__device__ __forceinline__ float grpsum16(float v) {
  v += rotr16<8>(v); v += rotr16<4>(v); v += rotr16<2>(v); v += rotr16<1>(v);
  return v;
}
__device__ __forceinline__ float grpmax16(float v) {
  v = fmaxf(v, rotr16<8>(v)); v = fmaxf(v, rotr16<4>(v));
  v = fmaxf(v, rotr16<2>(v)); v = fmaxf(v, rotr16<1>(v));
  return v;
}

// all-reduce over the 4 row-group lanes of a column (n, n+16, n+32, n+48):
// pure VALU via permlane swaps (s_nop covers VALU-write -> permlane-read).
__device__ __forceinline__ float colsum(float s) {
  float t = s;
  asm("s_nop 1\n\t"
      "v_permlane16_swap_b32 %0, %1" : "+v"(s), "+v"(t));
  s = s + t;
  float u = s;
  asm("s_nop 1\n\t"
      "v_permlane32_swap_b32 %0, %1" : "+v"(s), "+v"(u));
  return s + u;
}

// shuffle a packed half4v (8B) within 16-lane groups
__device__ __forceinline__ half4v shfl4h(half4v v, int src) {
  int2 iv = __builtin_bit_cast(int2, v);
  iv.x = __shfl(iv.x, src, 16);
  iv.y = __shfl(iv.y, src, 16);
  return __builtin_bit_cast(half4v, iv);
}

// leaf step: raw = Pi[m][pos] * B[m][x]; normalize per column; RETURN nu.
__device__ __forceinline__ half4v leafstep(const float* __restrict__ sB, int m0,
                                           int xv, float p0, float p1,
                                           float p2, float p3, float& nuOut) {
  f32x4 b = *(const f32x4*)(sB + xv + m0);
  float r0 = b[0] * p0, r1 = b[1] * p1, r2 = b[2] * p2, r3 = b[3] * p3;
  float nu = colsum((r0 + r1) + (r2 + r3));
  nuOut = nu;
  float rc = RCP(nu);
  half4v p;
  p[0] = (__fp16)(r0 * rc); p[1] = (__fp16)(r1 * rc);
  p[2] = (__fp16)(r2 * rc); p[3] = (__fp16)(r3 * rc);
  return p;
}

// internal step: D = A*[pkL;pkR] (one MFMA) * B[m][x]; logs CHILDREN's nus
// (paired); returns own nu unlogged.
__device__ __forceinline__ half4v istep(const float* __restrict__ sB, int m0,
                                        int xv, half8 af, half4v pl, half4v pr,
                                        float nuL, float nuR,
                                        float& nuOut, float& ll) {
  half8 bb;
  bb[0] = pl[0]; bb[1] = pl[1]; bb[2] = pl[2]; bb[3] = pl[3];
  bb[4] = pr[0]; bb[5] = pr[1]; bb[6] = pr[2]; bb[7] = pr[3];
  f32x4 z = {0.f, 0.f, 0.f, 0.f};
  f32x4 acc = __builtin_amdgcn_mfma_f32_16x16x32_f16(af, bb, z, 0, 0, 0);
  ll += __log2f(nuL * nuR);
  f32x4 b = *(const f32x4*)(sB + xv + m0);
  float r0 = acc[0] * b[0], r1 = acc[1] * b[1];
  float r2 = acc[2] * b[2], r3 = acc[3] * b[3];
  float nu = colsum((r0 + r1) + (r2 + r3));
  nuOut = nu;
  float rc = RCP(nu);
  half4v p;
  p[0] = (__fp16)(r0 * rc); p[1] = (__fp16)(r1 * rc);
  p[2] = (__fp16)(r2 * rc); p[3] = (__fp16)(r3 * rc);
  return p;
}

// intra-wave top step: UW parents per wave; children = cols 2tc,2tc+1 of q
// (no barrier -- pure shfl + MFMA). Masked log for c < UW.
template<int UW>
__device__ __forceinline__ half4v wstep(const float* __restrict__ sB,
                                        const int* __restrict__ xs,
                                        int nodebase, int m0, int c,
                                        half8 af, half4v q, float& ll) {
  int tc = (UW == 8) ? (c & 7) : ((c < UW) ? c : (UW - 1));
  int xv = xs[nodebase + tc] * SBS;
  half4v uL = shfl4h(q, 2 * tc);
  half4v uR = shfl4h(q, 2 * tc + 1);
  half8 bb;
  bb[0] = uL[0]; bb[1] = uL[1]; bb[2] = uL[2]; bb[3] = uL[3];
  bb[4] = uR[0]; bb[5] = uR[1]; bb[6] = uR[2]; bb[7] = uR[3];
  f32x4 z = {0.f, 0.f, 0.f, 0.f};
  f32x4 acc = __builtin_amdgcn_mfma_f32_16x16x32_f16(af, bb, z, 0, 0, 0);
  f32x4 b = *(const f32x4*)(sB + xv + m0);
  float r0 = acc[0] * b[0], r1 = acc[1] * b[1];
  float r2 = acc[2] * b[2], r3 = acc[3] * b[3];
  float nu = colsum((r0 + r1) + (r2 + r3));
  float rc = RCP(nu);
  if (c < UW) ll += __log2f(nu);
  half4v p;
  p[0] = (__fp16)(r0 * rc); p[1] = (__fp16)(r1 * rc);
  p[2] = (__fp16)(r2 * rc); p[3] = (__fp16)(r3 * rc);
  return p;
}

// LDS-based top step (levels 1, 0 only): children read from LDS (fp32).
__device__ __forceinline__ void topstep(const float* __restrict__ rb, int rs,
                                        float* wb, int ws, int U, int xv,
                                        const float* __restrict__ sB, int m0,
                                        int col, half8 af, float& ll) {
  bool valid = col < U;
  int tc = valid ? col : 0;
  half8 bb;
  #pragma unroll
  for (int i = 0; i < 4; ++i) {
    bb[i]     = (__fp16)rb[(m0 + i) * rs + 2 * tc];
    bb[4 + i] = (__fp16)rb[(m0 + i) * rs + 2 * tc + 1];
  }
  f32x4 z = {0.f, 0.f, 0.f, 0.f};
  f32x4 acc = __builtin_amdgcn_mfma_f32_16x16x32_f16(af, bb, z, 0, 0, 0);
  f32x4 b = *(const f32x4*)(sB + xv + m0);
  float r0 = acc[0] * b[0], r1 = acc[1] * b[1];
  float r2 = acc[2] * b[2], r3 = acc[3] * b[3];
  float nu = colsum((r0 + r1) + (r2 + r3));
  float rc = RCP(nu);
  if (valid) {
    ll += __log2f(nu);
    if (wb) {
      wb[(m0 + 0) * ws + col] = r0 * rc;
      wb[(m0 + 1) * ws + col] = r1 * rc;
      wb[(m0 + 2) * ws + col] = r2 * rc;
      wb[(m0 + 3) * ws + col] = r3 * rc;
    }
  }
  __syncthreads();
}

__global__ __launch_bounds__(256, 4) void htmm_fwd_kernel(
    const float* __restrict__ lA,   // (16,16,2,8)
    const float* __restrict__ lB,   // (16,256,8)
    const float* __restrict__ lPi,  // (16,2,8)
    const float* __restrict__ lSP,  // (2,8)
    const int*   __restrict__ x,    // (128*1023,)
    float*       __restrict__ out)  // (128,8)
{
  __shared__ float sB[256 * SBS];   // normalized B, [m_obs][state], stride 20
  __shared__ float sA[2 * 16 * 16]; // normalized A, [l][b][a]
  __shared__ float sPi[32];         // [l][state]
  __shared__ int   xls[1024];       // staged x (shift +1 for alignment)
  __shared__ float topL2[16 * 5];   // level-2 beliefs, [state][wave]
  __shared__ float topL1[16 * 3];   // level-1 beliefs
  __shared__ float red[4];

  const int tid = threadIdx.x;
  const int bid = blockIdx.x;       // tree*8 + g
  const int T   = bid >> 3;
  const int g   = bid & 7;
  const int lane = tid & 63;
  const int wv   = tid >> 6;
  const int c    = lane & 15;       // column within wave / out-state m
  const int col  = (wv << 4) | c;   // subtree id 0..63
  const int m0   = (lane >> 4) << 2;// row base 0,4,8,12
  const int a    = tid & 15;        // prologue lane-state
  const int grp  = tid >> 4;        // prologue group
  const long base = (long)T * NPT_;

  // ---- stage x into LDS, fully coalesced (4 dword loads / thread) ----
  #pragma unroll
  for (int j = 0; j < 4; ++j) {
    int idx = tid + 256 * j;
    if (idx < NPT_) xls[idx + 1] = x[base + idx];
  }

  // ---- SP softmax ----
  float s0 = lSP[g], s1 = lSP[G_ + g];
  float sm = fmaxf(s0, s1);
  float e0 = __expf(s0 - sm), e1 = __expf(s1 - sm);
  float inv = RCP(e0 + e1);
  const float SP0 = e0 * inv, SP1 = e1 * inv;

  // ---- A softmax over axis 0 (lanes = a), column b = grp ----
  #pragma unroll
  for (int l = 0; l < 2; ++l) {
    float v = lA[a * 256 + grp * 16 + l * 8 + g];
    float m = grpmax16(v);
    float e = __expf(v - m);
    float s = grpsum16(e);
    sA[(l * 16 + grp) * 16 + a] = e * RCP(s);
  }
  // ---- Pi softmax over axis 0 ----
  if (grp < 2) {
    float v = lPi[a * 16 + grp * 8 + g];
    float m = grpmax16(v);
    float e = __expf(v - m);
    float s = grpsum16(e);
    sPi[grp * 16 + a] = e * RCP(s);
  }
  // ---- B softmax over axis 1 (M): row c = grp, lane a covers m = a+16k ----
  {
    const int cc = grp;
    float vv[16];
    float mx = -1e30f;
    #pragma unroll
    for (int k = 0; k < 16; ++k) {
      vv[k] = lB[cc * (256 * G_) + (a + 16 * k) * G_ + g];
      mx = fmaxf(mx, vv[k]);
    }
    mx = grpmax16(mx);
    float ssum = 0.f;
    #pragma unroll
    for (int k = 0; k < 16; ++k) { vv[k] = __expf(vv[k] - mx); ssum += vv[k]; }
    ssum = grpsum16(ssum);
    float is = RCP(ssum);
    #pragma unroll
    for (int k = 0; k < 16; ++k) sB[(a + 16 * k) * SBS + cc] = vv[k] * is;
  }
  __syncthreads();

  const int* xs = xls + 1;          // xs[i] == x[base + i]

  // ---- A-fragment: af[i<4] = W0[m=c][b=m0+i], af[i>=4] = W1[m=c][b=m0+i-4]
  half8 af;
  #pragma unroll
  for (int i = 0; i < 4; ++i) {
    af[i]     = (__fp16)(sA[(m0 + i) * 16 + c] * SP0);
    af[4 + i] = (__fp16)(sA[(16 + m0 + i) * 16 + c] * SP1);
  }
  // leaf Pi values for this lane's 4 rows
  const float pi00 = sPi[m0 + 0], pi01 = sPi[m0 + 1];
  const float pi02 = sPi[m0 + 2], pi03 = sPi[m0 + 3];
  const float pi10 = sPi[16 + m0 + 0], pi11 = sPi[16 + m0 + 1];
  const float pi12 = sPi[16 + m0 + 2], pi13 = sPi[16 + m0 + 3];

  // ---- subtree indices from LDS (aligned groups) ----
  int xl[8], x8v[4], x7v[2];
  #pragma unroll
  for (int j = 0; j < 8; ++j) xl[j] = xs[511 + 8 * col + j] * SBS;
  #pragma unroll
  for (int t = 0; t < 4; ++t) x8v[t] = xs[255 + 4 * col + t] * SBS;
  #pragma unroll
  for (int t = 0; t < 2; ++t) x7v[t] = xs[127 + 2 * col + t] * SBS;
  const int x6v = xs[63 + col] * SBS;

  float ll = 0.f;

  // ---- depth-4 subtree, post-order, all 64 columns lockstep ----
  half4v t0, t1, p80, p81, q0, q1;
  float nl0, nl1, n80, n81, n70, n71;
  t0 = leafstep(sB, m0, xl[0], pi00, pi01, pi02, pi03, nl0);
  t1 = leafstep(sB, m0, xl[1], pi10, pi11, pi12, pi13, nl1);
  p80 = istep(sB, m0, x8v[0], af, t0, t1, nl0, nl1, n80, ll);
  t0 = leafstep(sB, m0, xl[2], pi00, pi01, pi02, pi03, nl0);
  t1 = leafstep(sB, m0, xl[3], pi10, pi11, pi12, pi13, nl1);
  p81 = istep(sB, m0, x8v[1], af, t0, t1, nl0, nl1, n81, ll);
  q0 = istep(sB, m0, x7v[0], af, p80, p81, n80, n81, n70, ll);
  t0 = leafstep(sB, m0, xl[4], pi00, pi01, pi02, pi03, nl0);
  t1 = leafstep(sB, m0, xl[5], pi10, pi11, pi12, pi13, nl1);
  p80 = istep(sB, m0, x8v[2], af, t0, t1, nl0, nl1, n80, ll);
  t0 = leafstep(sB, m0, xl[6], pi00, pi01, pi02, pi03, nl0);
  t1 = leafstep(sB, m0, xl[7], pi10, pi11, pi12, pi13, nl1);
  p81 = istep(sB, m0, x8v[3], af, t0, t1, nl0, nl1, n81, ll);
  q1 = istep(sB, m0, x7v[1], af, p80, p81, n80, n81, n71, ll);

  // ---- subtree root (level 6): stays in registers ----
  half4v q6;
  {
    half8 bb;
    bb[0] = q0[0]; bb[1] = q0[1]; bb[2] = q0[2]; bb[3] = q0[3];
    bb[4] = q1[0]; bb[5] = q1[1]; bb[6] = q1[2]; bb[7] = q1[3];
    f32x4 z = {0.f, 0.f, 0.f, 0.f};
    f32x4 acc = __builtin_amdgcn_mfma_f32_16x16x32_f16(af, bb, z, 0, 0, 0);
    f32x4 b = *(const f32x4*)(sB + x6v + m0);
    float r0 = acc[0] * b[0], r1 = acc[1] * b[1];
    float r2 = acc[2] * b[2], r3 = acc[3] * b[3];
    float nu = colsum((r0 + r1) + (r2 + r3));
    ll += __log2f(n70 * n71 * nu);   // triple-paired log, >= ~1e-24
    float rc = RCP(nu);
    q6[0] = (__fp16)(r0 * rc); q6[1] = (__fp16)(r1 * rc);
    q6[2] = (__fp16)(r2 * rc); q6[3] = (__fp16)(r3 * rc);
  }

  // ---- top levels 5..2: intra-wave, barrier-free ----
  half4v q5 = wstep<8>(sB, xs, 31 + 8 * wv, m0, c, af, q6, ll);
  half4v q4 = wstep<4>(sB, xs, 15 + 4 * wv, m0, c, af, q5, ll);
  half4v q3 = wstep<2>(sB, xs,  7 + 2 * wv, m0, c, af, q4, ll);
  {  // level 2: one node per wave -> LDS
    int xv = xs[3 + wv] * SBS;
    half4v uL = shfl4h(q3, 0);
    half4v uR = shfl4h(q3, 1);
    half8 bb;
    bb[0] = uL[0]; bb[1] = uL[1]; bb[2] = uL[2]; bb[3] = uL[3];
    bb[4] = uR[0]; bb[5] = uR[1]; bb[6] = uR[2]; bb[7] = uR[3];
    f32x4 z = {0.f, 0.f, 0.f, 0.f};
    f32x4 acc = __builtin_amdgcn_mfma_f32_16x16x32_f16(af, bb, z, 0, 0, 0);
    f32x4 b = *(const f32x4*)(sB + xv + m0);
    float r0 = acc[0] * b[0], r1 = acc[1] * b[1];
    float r2 = acc[2] * b[2], r3 = acc[3] * b[3];
    float nu = colsum((r0 + r1) + (r2 + r3));
    float rc = RCP(nu);
    if (c == 0) {
      ll += __log2f(nu);
      topL2[(m0 + 0) * 5 + wv] = r0 * rc;
      topL2[(m0 + 1) * 5 + wv] = r1 * rc;
      topL2[(m0 + 2) * 5 + wv] = r2 * rc;
      topL2[(m0 + 3) * 5 + wv] = r3 * rc;
    }
  }
  __syncthreads();

  // ---- levels 1, 0 (cross-wave, LDS) ----
  int xvL1 = xs[1 + ((col < 2) ? col : 0)] * SBS;
  topstep(topL2, 5, topL1, 3, 2, xvL1, sB, m0, col, af, ll);
  int xvL0 = xs[0] * SBS;
  topstep(topL1, 3, nullptr, 0, 1, xvL0, sB, m0, col, af, ll);

  // ---- block reduce; each nu logged by 4 lane-replicas -> /4; log2 -> ln --
  float v = ll;
  #pragma unroll
  for (int off = 32; off > 0; off >>= 1) v += __shfl_down(v, off, 64);
  if (lane == 0) red[wv] = v;
  __syncthreads();
  if (tid == 0)
    out[bid] = (red[0] + red[1] + red[2] + red[3]) *
               (0.6931471805599453f * 0.25f);
}

extern "C" void kernel_launch(void* const* d_in, const int* in_sizes, int n_in,
                              void* d_out, int out_size, void* d_ws, size_t ws_size,
                              hipStream_t stream) {
  const float* lA  = (const float*)d_in[0];
  const float* lB  = (const float*)d_in[1];
  const float* lPi = (const float*)d_in[2];
  const float* lSP = (const float*)d_in[3];
  const int*   x   = (const int*)d_in[4];
  float* out = (float*)d_out;
  htmm_fwd_kernel<<<dim3(NT_ * G_), dim3(256), 0, stream>>>(lA, lB, lPi, lSP, x, out);
}